// Round 1
// baseline (752.346 us; speedup 1.0000x reference)
//
#include <hip/hip_runtime.h>

// PinConv pipeline, fp32 baseline.
// Stages: GEMM1+relu -> colstats -> bn coefs -> edge scatter (atomics) ->
//         concat[feat|agg] -> GEMM2+relu -> colstats -> bn coefs -> rownorm.

#define BN_EPS 1e-5f

// ---------------------------------------------------------------------------
// Y = relu(A @ B^T + bias); A: [N][lda], B: [128][K] row-major, Y: [N][128]
// Tile: 64 rows x 128 cols per block, 256 threads, K-chunks of 64.
template<int K>
__global__ __launch_bounds__(256) void gemm_relu(
    const float* __restrict__ A, int lda,
    const float* __restrict__ B,
    const float* __restrict__ bias,
    float* __restrict__ Y, int N)
{
    __shared__ float As[64][65];    // padded: stride 65 -> conflict-free
    __shared__ float Bs[64][132];   // B^T chunk: Bs[kk][c], stride 132 (16B-aligned rows)

    const int tid = threadIdx.x;
    const int cg  = tid & 7;    // col group: cols cg*4 + j*32 + m
    const int rr  = tid >> 3;   // row-in-tile 0..31 (also handles rr+32)
    const int r0  = blockIdx.x * 64;

    float4 acc0[4], acc1[4];
#pragma unroll
    for (int j = 0; j < 4; ++j) {
        acc0[j] = make_float4(0.f, 0.f, 0.f, 0.f);
        acc1[j] = make_float4(0.f, 0.f, 0.f, 0.f);
    }

    for (int kc = 0; kc < K; kc += 64) {
        // stage A tile 64x64 (coalesced 64-wide)
#pragma unroll
        for (int i = 0; i < 16; ++i) {
            int idx = i * 256 + tid;       // 0..4095
            int row = idx >> 6;
            int kk  = idx & 63;
            int gr  = r0 + row;
            As[row][kk] = (gr < N) ? A[(size_t)gr * lda + kc + kk] : 0.f;
        }
        // stage B chunk transposed: Bs[kk][c] = B[c][kc+kk]
#pragma unroll
        for (int i = 0; i < 32; ++i) {
            int idx = i * 256 + tid;       // 0..8191
            int c   = idx >> 6;            // 0..127
            int kk  = idx & 63;
            Bs[kk][c] = B[(size_t)c * K + kc + kk];
        }
        __syncthreads();

#pragma unroll 8
        for (int kk = 0; kk < 64; ++kk) {
            float a0 = As[rr][kk];
            float a1 = As[rr + 32][kk];
            const float4* brow = (const float4*)&Bs[kk][0];
#pragma unroll
            for (int j = 0; j < 4; ++j) {
                float4 b = brow[cg + j * 8];
                acc0[j].x = fmaf(a0, b.x, acc0[j].x);
                acc0[j].y = fmaf(a0, b.y, acc0[j].y);
                acc0[j].z = fmaf(a0, b.z, acc0[j].z);
                acc0[j].w = fmaf(a0, b.w, acc0[j].w);
                acc1[j].x = fmaf(a1, b.x, acc1[j].x);
                acc1[j].y = fmaf(a1, b.y, acc1[j].y);
                acc1[j].z = fmaf(a1, b.z, acc1[j].z);
                acc1[j].w = fmaf(a1, b.w, acc1[j].w);
            }
        }
        __syncthreads();
    }

    // epilogue: +bias, relu, store
    const int gr0 = r0 + rr;
    const int gr1 = r0 + rr + 32;
#pragma unroll
    for (int j = 0; j < 4; ++j) {
        int c = cg * 4 + j * 32;
        float4 bz = *(const float4*)&bias[c];
        float4 v0 = acc0[j], v1 = acc1[j];
        v0.x = fmaxf(v0.x + bz.x, 0.f); v0.y = fmaxf(v0.y + bz.y, 0.f);
        v0.z = fmaxf(v0.z + bz.z, 0.f); v0.w = fmaxf(v0.w + bz.w, 0.f);
        v1.x = fmaxf(v1.x + bz.x, 0.f); v1.y = fmaxf(v1.y + bz.y, 0.f);
        v1.z = fmaxf(v1.z + bz.z, 0.f); v1.w = fmaxf(v1.w + bz.w, 0.f);
        if (gr0 < N) *(float4*)&Y[(size_t)gr0 * 128 + c] = v0;
        if (gr1 < N) *(float4*)&Y[(size_t)gr1 * 128 + c] = v1;
    }
}

// ---------------------------------------------------------------------------
// Per-column sum / sumsq over [N][128], fp64 atomic accumulation.
__global__ __launch_bounds__(256) void colstats(
    const float* __restrict__ Y, int N,
    double* __restrict__ sum, double* __restrict__ sumsq)
{
    __shared__ float sh[2][256];
    const int col  = threadIdx.x & 127;
    const int half = threadIdx.x >> 7;
    const int rbeg = blockIdx.x * 256 + half;
    const int rend = min(N, blockIdx.x * 256 + 256);
    float s = 0.f, q = 0.f;
    for (int r = rbeg; r < rend; r += 2) {
        float v = Y[(size_t)r * 128 + col];
        s += v; q = fmaf(v, v, q);
    }
    sh[0][threadIdx.x] = s;
    sh[1][threadIdx.x] = q;
    __syncthreads();
    if (half == 0) {
        s = sh[0][col] + sh[0][col + 128];
        q = sh[1][col] + sh[1][col + 128];
        atomicAdd(&sum[col], (double)s);
        atomicAdd(&sumsq[col], (double)q);
    }
}

// ---------------------------------------------------------------------------
// Fold mean/var/gamma/beta into per-column affine: h = a[c]*y + b[c]
__global__ void bn_coef(const double* __restrict__ sum, const double* __restrict__ sumsq,
                        const float* __restrict__ gamma, const float* __restrict__ beta,
                        float* __restrict__ a, float* __restrict__ b, float invN)
{
    int j = threadIdx.x;  // 128 threads
    float mean = (float)(sum[j] * (double)invN);
    float var  = (float)(sumsq[j] * (double)invN) - mean * mean;
    float s = rsqrtf(var + BN_EPS) * gamma[j];
    a[j] = s;
    b[j] = fmaf(-mean, s, beta[j]);
}

// ---------------------------------------------------------------------------
// Edge scatter: num[dst] += w_e * h[src], den[dst] += w_e.  One wave per edge.
__global__ __launch_bounds__(256) void edge_scatter(
    const float* __restrict__ y1,
    const float* __restrict__ a1, const float* __restrict__ b1,
    const float* __restrict__ w,
    const int* __restrict__ src, const int* __restrict__ dst,
    float* __restrict__ num, float* __restrict__ den, int E)
{
    const int e    = (int)((blockIdx.x * (unsigned)blockDim.x + threadIdx.x) >> 6);
    const int lane = threadIdx.x & 63;
    if (e >= E) return;
    const int s = src[e];
    const int d = dst[e];
    const float we = w[e];
    const size_t sb = (size_t)s * 128, db = (size_t)d * 128;
    float h0 = fmaf(a1[lane],      y1[sb + lane],      b1[lane]);
    float h1 = fmaf(a1[lane + 64], y1[sb + lane + 64], b1[lane + 64]);
    atomicAdd(&num[db + lane],      we * h0);
    atomicAdd(&num[db + lane + 64], we * h1);
    if (lane == 0) atomicAdd(&den[d], we);
}

// ---------------------------------------------------------------------------
// A2[i] = [feat[i] | agg[i]], agg = den!=0 ? num/den : h
__global__ __launch_bounds__(256) void build_A2(
    const float* __restrict__ feat, const float* __restrict__ y1,
    const float* __restrict__ num, const float* __restrict__ den,
    const float* __restrict__ a1, const float* __restrict__ b1,
    float* __restrict__ A2, int N)
{
    int idx = blockIdx.x * blockDim.x + threadIdx.x;
    if (idx >= N * 128) return;
    int row = idx >> 7, c = idx & 127;
    float d = den[row];
    float h = fmaf(a1[c], y1[idx], b1[c]);
    float agg = (d != 0.f) ? num[idx] / d : h;
    A2[(size_t)row * 256 + c]       = feat[idx];
    A2[(size_t)row * 256 + 128 + c] = agg;
}

// ---------------------------------------------------------------------------
// Apply bn2 affine, L2-normalize each row. One wave per row.
__global__ __launch_bounds__(256) void finalize(
    const float* __restrict__ Y2,
    const float* __restrict__ a2, const float* __restrict__ b2,
    float* __restrict__ out, int N)
{
    const int row  = (int)((blockIdx.x * (unsigned)blockDim.x + threadIdx.x) >> 6);
    const int lane = threadIdx.x & 63;
    if (row >= N) return;
    const size_t base = (size_t)row * 128;
    float v0 = fmaf(a2[lane],      Y2[base + lane],      b2[lane]);
    float v1 = fmaf(a2[lane + 64], Y2[base + lane + 64], b2[lane + 64]);
    float ss = fmaf(v0, v0, v1 * v1);
#pragma unroll
    for (int o = 32; o; o >>= 1) ss += __shfl_xor(ss, o, 64);
    float nrm = sqrtf(ss);
    float inv = (nrm == 0.f) ? 1.f : 1.f / nrm;
    out[base + lane]      = v0 * inv;
    out[base + lane + 64] = v1 * inv;
}

// ---------------------------------------------------------------------------
extern "C" void kernel_launch(void* const* d_in, const int* in_sizes, int n_in,
                              void* d_out, int out_size, void* d_ws, size_t ws_size,
                              hipStream_t stream)
{
    const float* feat   = (const float*)d_in[0];
    const float* w      = (const float*)d_in[1];
    const float* Q_w    = (const float*)d_in[2];
    const float* Q_b    = (const float*)d_in[3];
    const float* W_w    = (const float*)d_in[4];
    const float* W_b    = (const float*)d_in[5];
    const float* gamma2 = (const float*)d_in[6];
    const float* beta2  = (const float*)d_in[7];
    const int*   src    = (const int*)d_in[8];
    const int*   dst    = (const int*)d_in[9];

    const int N = in_sizes[0] / 128;   // 50000
    const int E = in_sizes[1];         // 800000

    // workspace layout (floats): y1/y2 [N*128] | A2 [N*256] | num [N*128] | den [N]
    //                            | stats (512 doubles) | coefs (512 floats)
    float* y1  = (float*)d_ws;                 // reused as y2 after build_A2
    float* A2  = y1  + (size_t)N * 128;
    float* num = A2  + (size_t)N * 256;
    float* den = num + (size_t)N * 128;
    double* stats = (double*)(den + N);        // byte offset divisible by 8 (N*4)
    double* sum1 = stats, *sumsq1 = stats + 128, *sum2 = stats + 256, *sumsq2 = stats + 384;
    float* coefs = (float*)(stats + 512);
    float* a1 = coefs, *b1 = coefs + 128, *a2 = coefs + 256, *b2 = coefs + 384;

    // zero num | den | stats | coefs (contiguous tail region)
    size_t zero_bytes = ((size_t)N * 128 + N) * sizeof(float)
                      + 512 * sizeof(double) + 512 * sizeof(float);
    hipMemsetAsync(num, 0, zero_bytes, stream);

    const float invN = 1.f / (float)N;
    const int gemm_blocks = (N + 63) / 64;

    gemm_relu<128><<<gemm_blocks, 256, 0, stream>>>(feat, 128, Q_w, Q_b, y1, N);
    colstats<<<(N + 255) / 256, 256, 0, stream>>>(y1, N, sum1, sumsq1);
    bn_coef<<<1, 128, 0, stream>>>(sum1, sumsq1, gamma2, beta2, a1, b1, invN);
    edge_scatter<<<(E + 3) / 4, 256, 0, stream>>>(y1, a1, b1, w, src, dst, num, den, E);
    build_A2<<<(N * 128 + 255) / 256, 256, 0, stream>>>(feat, y1, num, den, a1, b1, A2, N);
    gemm_relu<256><<<gemm_blocks, 256, 0, stream>>>(A2, 256, W_w, W_b, y1 /*=y2*/, N);
    colstats<<<(N + 255) / 256, 256, 0, stream>>>(y1, N, sum2, sumsq2);
    bn_coef<<<1, 128, 0, stream>>>(sum2, sumsq2, gamma2, beta2, a2, b2, invN);
    finalize<<<(N + 3) / 4, 256, 0, stream>>>(y1, a2, b2, (float*)d_out, N);
}

// Round 2
// 537.230 us; speedup vs baseline: 1.4004x; 1.4004x over previous
//
#include <hip/hip_runtime.h>
#include <stdint.h>

// PinConv pipeline, fp32, CSR-gather edge aggregation (no fp32 atomics).
// Stages: GEMM1+relu -> colstats -> bn coefs
//         CSR build (count -> scan -> fill)
//         gather+concat (writes A2 = [feat|agg] directly)
//         GEMM2+relu -> colstats -> bn coefs -> rownorm.

#define BN_EPS 1e-5f

// ---------------------------------------------------------------------------
// Y = relu(A @ B^T + bias); A: [N][lda], B: [128][K] row-major, Y: [N][128]
template<int K>
__global__ __launch_bounds__(256) void gemm_relu(
    const float* __restrict__ A, int lda,
    const float* __restrict__ B,
    const float* __restrict__ bias,
    float* __restrict__ Y, int N)
{
    __shared__ float As[64][65];
    __shared__ float Bs[64][132];

    const int tid = threadIdx.x;
    const int cg  = tid & 7;
    const int rr  = tid >> 3;
    const int r0  = blockIdx.x * 64;

    float4 acc0[4], acc1[4];
#pragma unroll
    for (int j = 0; j < 4; ++j) {
        acc0[j] = make_float4(0.f, 0.f, 0.f, 0.f);
        acc1[j] = make_float4(0.f, 0.f, 0.f, 0.f);
    }

    for (int kc = 0; kc < K; kc += 64) {
#pragma unroll
        for (int i = 0; i < 16; ++i) {
            int idx = i * 256 + tid;
            int row = idx >> 6;
            int kk  = idx & 63;
            int gr  = r0 + row;
            As[row][kk] = (gr < N) ? A[(size_t)gr * lda + kc + kk] : 0.f;
        }
#pragma unroll
        for (int i = 0; i < 32; ++i) {
            int idx = i * 256 + tid;
            int c   = idx >> 6;
            int kk  = idx & 63;
            Bs[kk][c] = B[(size_t)c * K + kc + kk];
        }
        __syncthreads();

#pragma unroll 8
        for (int kk = 0; kk < 64; ++kk) {
            float a0 = As[rr][kk];
            float a1 = As[rr + 32][kk];
            const float4* brow = (const float4*)&Bs[kk][0];
#pragma unroll
            for (int j = 0; j < 4; ++j) {
                float4 b = brow[cg + j * 8];
                acc0[j].x = fmaf(a0, b.x, acc0[j].x);
                acc0[j].y = fmaf(a0, b.y, acc0[j].y);
                acc0[j].z = fmaf(a0, b.z, acc0[j].z);
                acc0[j].w = fmaf(a0, b.w, acc0[j].w);
                acc1[j].x = fmaf(a1, b.x, acc1[j].x);
                acc1[j].y = fmaf(a1, b.y, acc1[j].y);
                acc1[j].z = fmaf(a1, b.z, acc1[j].z);
                acc1[j].w = fmaf(a1, b.w, acc1[j].w);
            }
        }
        __syncthreads();
    }

    const int gr0 = r0 + rr;
    const int gr1 = r0 + rr + 32;
#pragma unroll
    for (int j = 0; j < 4; ++j) {
        int c = cg * 4 + j * 32;
        float4 bz = *(const float4*)&bias[c];
        float4 v0 = acc0[j], v1 = acc1[j];
        v0.x = fmaxf(v0.x + bz.x, 0.f); v0.y = fmaxf(v0.y + bz.y, 0.f);
        v0.z = fmaxf(v0.z + bz.z, 0.f); v0.w = fmaxf(v0.w + bz.w, 0.f);
        v1.x = fmaxf(v1.x + bz.x, 0.f); v1.y = fmaxf(v1.y + bz.y, 0.f);
        v1.z = fmaxf(v1.z + bz.z, 0.f); v1.w = fmaxf(v1.w + bz.w, 0.f);
        if (gr0 < N) *(float4*)&Y[(size_t)gr0 * 128 + c] = v0;
        if (gr1 < N) *(float4*)&Y[(size_t)gr1 * 128 + c] = v1;
    }
}

// ---------------------------------------------------------------------------
__global__ __launch_bounds__(256) void colstats(
    const float* __restrict__ Y, int N,
    double* __restrict__ sum, double* __restrict__ sumsq)
{
    __shared__ float sh[2][256];
    const int col  = threadIdx.x & 127;
    const int half = threadIdx.x >> 7;
    const int rbeg = blockIdx.x * 256 + half;
    const int rend = min(N, blockIdx.x * 256 + 256);
    float s = 0.f, q = 0.f;
    for (int r = rbeg; r < rend; r += 2) {
        float v = Y[(size_t)r * 128 + col];
        s += v; q = fmaf(v, v, q);
    }
    sh[0][threadIdx.x] = s;
    sh[1][threadIdx.x] = q;
    __syncthreads();
    if (half == 0) {
        s = sh[0][col] + sh[0][col + 128];
        q = sh[1][col] + sh[1][col + 128];
        atomicAdd(&sum[col], (double)s);
        atomicAdd(&sumsq[col], (double)q);
    }
}

// ---------------------------------------------------------------------------
__global__ void bn_coef(const double* __restrict__ sum, const double* __restrict__ sumsq,
                        const float* __restrict__ gamma, const float* __restrict__ beta,
                        float* __restrict__ a, float* __restrict__ b, float invN)
{
    int j = threadIdx.x;  // 128 threads
    float mean = (float)(sum[j] * (double)invN);
    float var  = (float)(sumsq[j] * (double)invN) - mean * mean;
    float s = rsqrtf(var + BN_EPS) * gamma[j];
    a[j] = s;
    b[j] = fmaf(-mean, s, beta[j]);
}

// ---------------------------------------------------------------------------
// CSR build: histogram of dst
__global__ __launch_bounds__(256) void k_count(
    const int* __restrict__ dst, int* __restrict__ cnt, int E)
{
    int e = blockIdx.x * 256 + threadIdx.x;
    if (e < E) atomicAdd(&cnt[dst[e]], 1);
}

// chunk=1024 per block (4 per thread), exclusive scan within chunk + block total
__global__ __launch_bounds__(256) void k_scan1(
    const int* __restrict__ cnt, int* __restrict__ offs, int* __restrict__ bsum, int N)
{
    __shared__ int sh[256];
    const int tid  = threadIdx.x;
    const int base = blockIdx.x * 1024 + tid * 4;
    int v[4], s = 0;
#pragma unroll
    for (int j = 0; j < 4; ++j) {
        v[j] = (base + j < N) ? cnt[base + j] : 0;
        s += v[j];
    }
    sh[tid] = s;
    __syncthreads();
    for (int o = 1; o < 256; o <<= 1) {      // Hillis-Steele inclusive scan
        int t = (tid >= o) ? sh[tid - o] : 0;
        __syncthreads();
        sh[tid] += t;
        __syncthreads();
    }
    int run = sh[tid] - s;                   // exclusive prefix for this thread
#pragma unroll
    for (int j = 0; j < 4; ++j) {
        if (base + j < N) offs[base + j] = run;
        run += v[j];
    }
    if (tid == 255) bsum[blockIdx.x] = sh[255];
}

__global__ void k_scan2(int* __restrict__ bsum, int nb)
{
    if (threadIdx.x == 0) {
        int run = 0;
        for (int i = 0; i < nb; ++i) { int t = bsum[i]; bsum[i] = run; run += t; }
    }
}

__global__ __launch_bounds__(256) void k_scan3(
    int* __restrict__ offs, int* __restrict__ cursor,
    const int* __restrict__ bsum, int N, int E)
{
    int i = blockIdx.x * 256 + threadIdx.x;
    if (i < N) {
        int o = offs[i] + bsum[i >> 10];
        offs[i] = o;
        cursor[i] = o;
    }
    if (i == 0) offs[N] = E;
}

__global__ __launch_bounds__(256) void k_fill(
    const int* __restrict__ src, const int* __restrict__ dst,
    const float* __restrict__ w, int* __restrict__ cursor,
    int* __restrict__ esrc, float* __restrict__ ew, int E)
{
    int e = blockIdx.x * 256 + threadIdx.x;
    if (e >= E) return;
    int p = atomicAdd(&cursor[dst[e]], 1);
    esrc[p] = src[e];
    ew[p]   = w[e];
}

// ---------------------------------------------------------------------------
// One wave per dst row: num = sum w_e * (a1*y1[src]+b1); writes A2=[feat|agg].
__global__ __launch_bounds__(256) void gather_A2(
    const float* __restrict__ y1, const float* __restrict__ feat,
    const float* __restrict__ a1v, const float* __restrict__ b1v,
    const int* __restrict__ offs, const int* __restrict__ esrc,
    const float* __restrict__ ew,
    float* __restrict__ A2, int N)
{
    const int r    = (int)((blockIdx.x * 256u + threadIdx.x) >> 6);
    const int lane = threadIdx.x & 63;
    if (r >= N) return;
    const float2 a = *(const float2*)&a1v[2 * lane];
    const float2 b = *(const float2*)&b1v[2 * lane];
    int p = offs[r];
    const int end = offs[r + 1];
    float nx = 0.f, ny = 0.f, den = 0.f;
    for (; p + 1 < end; p += 2) {
        int   s0 = esrc[p],  s1 = esrc[p + 1];
        float w0 = ew[p],    w1 = ew[p + 1];
        float2 ya = *(const float2*)&y1[(size_t)s0 * 128 + 2 * lane];
        float2 yb = *(const float2*)&y1[(size_t)s1 * 128 + 2 * lane];
        nx = fmaf(w0, fmaf(a.x, ya.x, b.x), nx);
        ny = fmaf(w0, fmaf(a.y, ya.y, b.y), ny);
        nx = fmaf(w1, fmaf(a.x, yb.x, b.x), nx);
        ny = fmaf(w1, fmaf(a.y, yb.y, b.y), ny);
        den += w0 + w1;
    }
    if (p < end) {
        int   s0 = esrc[p];
        float w0 = ew[p];
        float2 ya = *(const float2*)&y1[(size_t)s0 * 128 + 2 * lane];
        nx = fmaf(w0, fmaf(a.x, ya.x, b.x), nx);
        ny = fmaf(w0, fmaf(a.y, ya.y, b.y), ny);
        den += w0;
    }
    float2 outv;
    if (den != 0.f) {
        float inv = 1.f / den;
        outv.x = nx * inv; outv.y = ny * inv;
    } else {
        float2 y = *(const float2*)&y1[(size_t)r * 128 + 2 * lane];
        outv.x = fmaf(a.x, y.x, b.x);
        outv.y = fmaf(a.y, y.y, b.y);
    }
    const size_t rb = (size_t)r * 256;
    *(float2*)&A2[rb + 2 * lane] = *(const float2*)&feat[(size_t)r * 128 + 2 * lane];
    *(float2*)&A2[rb + 128 + 2 * lane] = outv;
}

// ---------------------------------------------------------------------------
__global__ __launch_bounds__(256) void finalize(
    const float* __restrict__ Y2,
    const float* __restrict__ a2, const float* __restrict__ b2,
    float* __restrict__ out, int N)
{
    const int row  = (int)((blockIdx.x * 256u + threadIdx.x) >> 6);
    const int lane = threadIdx.x & 63;
    if (row >= N) return;
    const size_t base = (size_t)row * 128;
    float v0 = fmaf(a2[lane],      Y2[base + lane],      b2[lane]);
    float v1 = fmaf(a2[lane + 64], Y2[base + lane + 64], b2[lane + 64]);
    float ss = fmaf(v0, v0, v1 * v1);
#pragma unroll
    for (int o = 32; o; o >>= 1) ss += __shfl_xor(ss, o, 64);
    float nrm = sqrtf(ss);
    float inv = (nrm == 0.f) ? 1.f : 1.f / nrm;
    out[base + lane]      = v0 * inv;
    out[base + lane + 64] = v1 * inv;
}

// ---------------------------------------------------------------------------
extern "C" void kernel_launch(void* const* d_in, const int* in_sizes, int n_in,
                              void* d_out, int out_size, void* d_ws, size_t ws_size,
                              hipStream_t stream)
{
    const float* feat   = (const float*)d_in[0];
    const float* w      = (const float*)d_in[1];
    const float* Q_w    = (const float*)d_in[2];
    const float* Q_b    = (const float*)d_in[3];
    const float* W_w    = (const float*)d_in[4];
    const float* W_b    = (const float*)d_in[5];
    const float* gamma2 = (const float*)d_in[6];
    const float* beta2  = (const float*)d_in[7];
    const int*   src    = (const int*)d_in[8];
    const int*   dst    = (const int*)d_in[9];

    const int N = in_sizes[0] / 128;   // 50000
    const int E = in_sizes[1];         // 800000

    // workspace layout
    float* y1     = (float*)d_ws;                    // N*128 (reused as y2)
    float* A2     = y1 + (size_t)N * 128;            // N*256
    int*   esrc   = (int*)(A2 + (size_t)N * 256);    // E
    float* ew     = (float*)(esrc + E);              // E
    int*   offs   = (int*)(ew + E);                  // N+1
    int*   cursor = offs + (N + 1);                  // N
    int*   cnt    = cursor + N;                      // N   <- zeroed
    int*   bsum   = cnt + N;                         // 64  <- zeroed
    uintptr_t sp  = ((uintptr_t)(bsum + 64) + 7) & ~(uintptr_t)7;
    double* stats = (double*)sp;                     // 512 <- zeroed
    double* sum1 = stats, *sumsq1 = stats + 128, *sum2 = stats + 256, *sumsq2 = stats + 384;
    float* coefs = (float*)(stats + 512);            // 512
    float* a1 = coefs, *b1 = coefs + 128, *a2 = coefs + 256, *b2 = coefs + 384;

    // zero cnt..stats (contiguous)
    size_t zero_bytes = (size_t)((char*)(stats + 512) - (char*)cnt);
    hipMemsetAsync(cnt, 0, zero_bytes, stream);

    const float invN = 1.f / (float)N;
    const int gemm_blocks = (N + 63) / 64;
    const int nchunks = (N + 1023) / 1024;

    gemm_relu<128><<<gemm_blocks, 256, 0, stream>>>(feat, 128, Q_w, Q_b, y1, N);
    colstats<<<(N + 255) / 256, 256, 0, stream>>>(y1, N, sum1, sumsq1);
    bn_coef<<<1, 128, 0, stream>>>(sum1, sumsq1, gamma2, beta2, a1, b1, invN);

    k_count<<<(E + 255) / 256, 256, 0, stream>>>(dst, cnt, E);
    k_scan1<<<nchunks, 256, 0, stream>>>(cnt, offs, bsum, N);
    k_scan2<<<1, 64, 0, stream>>>(bsum, nchunks);
    k_scan3<<<(N + 255) / 256, 256, 0, stream>>>(offs, cursor, bsum, N, E);
    k_fill<<<(E + 255) / 256, 256, 0, stream>>>(src, dst, w, cursor, esrc, ew, E);

    gather_A2<<<(N * 64 + 255) / 256, 256, 0, stream>>>(
        y1, feat, a1, b1, offs, esrc, ew, A2, N);

    gemm_relu<256><<<gemm_blocks, 256, 0, stream>>>(A2, 256, W_w, W_b, y1 /*=y2*/, N);
    colstats<<<(N + 255) / 256, 256, 0, stream>>>(y1, N, sum2, sumsq2);
    bn_coef<<<1, 128, 0, stream>>>(sum2, sumsq2, gamma2, beta2, a2, b2, invN);
    finalize<<<(N + 3) / 4, 256, 0, stream>>>(y1, a2, b2, (float*)d_out, N);
}

// Round 3
// 384.848 us; speedup vs baseline: 1.9549x; 1.3960x over previous
//
#include <hip/hip_runtime.h>
#include <stdint.h>

// PinConv pipeline: bf16-MFMA GEMMs + CSR-gather aggregation.
// Stages: cast(feat,Qw,Ww)->bf16 | GEMM1(MFMA)+relu -> colstats -> bn coefs
//         CSR build (count -> scan -> fill) | gather+concat -> A2 (bf16)
//         GEMM2(MFMA)+relu -> colstats -> bn coefs -> rownorm.

#define BN_EPS 1e-5f

typedef __attribute__((ext_vector_type(8))) short bf16x8;
typedef __attribute__((ext_vector_type(4))) float f32x4;

static __device__ __forceinline__ unsigned short f2bf(float f) {
    uint32_t u = __builtin_bit_cast(uint32_t, f);
    u += 0x7fffu + ((u >> 16) & 1u);          // round-to-nearest-even
    return (unsigned short)(u >> 16);
}

// ---------------------------------------------------------------------------
__global__ __launch_bounds__(256) void f32_to_bf16(
    const float* __restrict__ in, unsigned short* __restrict__ out, int n)
{
    int i = (blockIdx.x * 256 + threadIdx.x) * 4;
    if (i + 3 < n) {
        float4 v = *(const float4*)(in + i);
        ushort4 o;
        o.x = f2bf(v.x); o.y = f2bf(v.y); o.z = f2bf(v.z); o.w = f2bf(v.w);
        *(ushort4*)(out + i) = o;
    } else {
        for (int j = i; j < n; ++j) out[j] = f2bf(in[j]);
    }
}

// ---------------------------------------------------------------------------
// Y = relu(A @ B^T + bias), A:[N][K] bf16, B:[128][K] bf16, Y:[N][128] f32.
// Block tile 64x128, 4 waves (2x2), wave tile 32x64, BK=64.
// MFMA 16x16x32_bf16: A frag m=lane&15,k=quad*8+j; B frag n=lane&15,k=quad*8+j;
// C/D: col=lane&15, row=quad*4+reg (m89/m91-verified mapping).
template<int K>
__global__ __launch_bounds__(256) void gemm_mfma(
    const unsigned short* __restrict__ A,
    const unsigned short* __restrict__ B,
    const float* __restrict__ bias,
    float* __restrict__ Y, int N)
{
    constexpr int SA = 72;   // LDS row stride (bf16): pad 64->72 breaks bank aliasing
    __shared__ unsigned short As[64 * SA];
    __shared__ unsigned short Bs[128 * SA];

    const int tid  = threadIdx.x;
    const int lane = tid & 63;
    const int wv   = tid >> 6;
    const int wr   = wv >> 1;      // wave row 0..1 (32 rows each)
    const int wc   = wv & 1;       // wave col 0..1 (64 cols each)
    const int m15  = lane & 15;
    const int quad = lane >> 4;
    const int r0   = blockIdx.x * 64;

    f32x4 acc[2][4];
#pragma unroll
    for (int rt = 0; rt < 2; ++rt)
#pragma unroll
        for (int ct = 0; ct < 4; ++ct)
            acc[rt][ct] = (f32x4){0.f, 0.f, 0.f, 0.f};

    for (int kc = 0; kc < K; kc += 64) {
        // stage A tile: 64 rows x 64 k (8 bf16 per 16B chunk), 2 iters
#pragma unroll
        for (int i = 0; i < 2; ++i) {
            int idx = i * 256 + tid;
            int row = idx >> 3, seg = idx & 7;
            int gr  = r0 + row; if (gr >= N) gr = N - 1;   // clamp: rows >=N unused
            uint4 v = *(const uint4*)(A + (size_t)gr * K + kc + seg * 8);
            *(uint4*)(As + row * SA + seg * 8) = v;
        }
        // stage B tile: 128 rows x 64 k, 4 iters
#pragma unroll
        for (int i = 0; i < 4; ++i) {
            int idx = i * 256 + tid;
            int row = idx >> 3, seg = idx & 7;
            uint4 v = *(const uint4*)(B + (size_t)row * K + kc + seg * 8);
            *(uint4*)(Bs + row * SA + seg * 8) = v;
        }
        __syncthreads();

#pragma unroll
        for (int ks = 0; ks < 64; ks += 32) {
            bf16x8 af[2], bfr[4];
#pragma unroll
            for (int rt = 0; rt < 2; ++rt)
                af[rt] = *(const bf16x8*)(As + (wr * 32 + rt * 16 + m15) * SA + ks + quad * 8);
#pragma unroll
            for (int ct = 0; ct < 4; ++ct)
                bfr[ct] = *(const bf16x8*)(Bs + (wc * 64 + ct * 16 + m15) * SA + ks + quad * 8);
#pragma unroll
            for (int rt = 0; rt < 2; ++rt)
#pragma unroll
                for (int ct = 0; ct < 4; ++ct)
                    acc[rt][ct] = __builtin_amdgcn_mfma_f32_16x16x32_bf16(
                        af[rt], bfr[ct], acc[rt][ct], 0, 0, 0);
        }
        __syncthreads();
    }

    // epilogue: +bias, relu, store fp32
#pragma unroll
    for (int ct = 0; ct < 4; ++ct) {
        int col = wc * 64 + ct * 16 + m15;
        float bz = bias[col];
#pragma unroll
        for (int rt = 0; rt < 2; ++rt) {
#pragma unroll
            for (int reg = 0; reg < 4; ++reg) {
                int row = r0 + wr * 32 + rt * 16 + quad * 4 + reg;
                if (row < N)
                    Y[(size_t)row * 128 + col] = fmaxf(acc[rt][ct][reg] + bz, 0.f);
            }
        }
    }
}

// ---------------------------------------------------------------------------
__global__ __launch_bounds__(256) void colstats(
    const float* __restrict__ Y, int N,
    double* __restrict__ sum, double* __restrict__ sumsq)
{
    __shared__ float sh[2][256];
    const int col  = threadIdx.x & 127;
    const int half = threadIdx.x >> 7;
    const int rbeg = blockIdx.x * 256 + half;
    const int rend = min(N, blockIdx.x * 256 + 256);
    float s = 0.f, q = 0.f;
    for (int r = rbeg; r < rend; r += 2) {
        float v = Y[(size_t)r * 128 + col];
        s += v; q = fmaf(v, v, q);
    }
    sh[0][threadIdx.x] = s;
    sh[1][threadIdx.x] = q;
    __syncthreads();
    if (half == 0) {
        s = sh[0][col] + sh[0][col + 128];
        q = sh[1][col] + sh[1][col + 128];
        atomicAdd(&sum[col], (double)s);
        atomicAdd(&sumsq[col], (double)q);
    }
}

// ---------------------------------------------------------------------------
__global__ void bn_coef(const double* __restrict__ sum, const double* __restrict__ sumsq,
                        const float* __restrict__ gamma, const float* __restrict__ beta,
                        float* __restrict__ a, float* __restrict__ b, float invN)
{
    int j = threadIdx.x;  // 128 threads
    float mean = (float)(sum[j] * (double)invN);
    float var  = (float)(sumsq[j] * (double)invN) - mean * mean;
    float s = rsqrtf(var + BN_EPS) * gamma[j];
    a[j] = s;
    b[j] = fmaf(-mean, s, beta[j]);
}

// ---------------------------------------------------------------------------
__global__ __launch_bounds__(256) void k_count(
    const int* __restrict__ dst, int* __restrict__ cnt, int E)
{
    int e = blockIdx.x * 256 + threadIdx.x;
    if (e < E) atomicAdd(&cnt[dst[e]], 1);
}

__global__ __launch_bounds__(256) void k_scan1(
    const int* __restrict__ cnt, int* __restrict__ offs, int* __restrict__ bsum, int N)
{
    __shared__ int sh[256];
    const int tid  = threadIdx.x;
    const int base = blockIdx.x * 1024 + tid * 4;
    int v[4], s = 0;
#pragma unroll
    for (int j = 0; j < 4; ++j) {
        v[j] = (base + j < N) ? cnt[base + j] : 0;
        s += v[j];
    }
    sh[tid] = s;
    __syncthreads();
    for (int o = 1; o < 256; o <<= 1) {
        int t = (tid >= o) ? sh[tid - o] : 0;
        __syncthreads();
        sh[tid] += t;
        __syncthreads();
    }
    int run = sh[tid] - s;
#pragma unroll
    for (int j = 0; j < 4; ++j) {
        if (base + j < N) offs[base + j] = run;
        run += v[j];
    }
    if (tid == 255) bsum[blockIdx.x] = sh[255];
}

__global__ void k_scan2(int* __restrict__ bsum, int nb)
{
    if (threadIdx.x == 0) {
        int run = 0;
        for (int i = 0; i < nb; ++i) { int t = bsum[i]; bsum[i] = run; run += t; }
    }
}

__global__ __launch_bounds__(256) void k_scan3(
    int* __restrict__ offs, int* __restrict__ cursor,
    const int* __restrict__ bsum, int N, int E)
{
    int i = blockIdx.x * 256 + threadIdx.x;
    if (i < N) {
        int o = offs[i] + bsum[i >> 10];
        offs[i] = o;
        cursor[i] = o;
    }
    if (i == 0) offs[N] = E;
}

__global__ __launch_bounds__(256) void k_fill(
    const int* __restrict__ src, const int* __restrict__ dst,
    const float* __restrict__ w, int* __restrict__ cursor,
    int* __restrict__ esrc, float* __restrict__ ew, int E)
{
    int e = blockIdx.x * 256 + threadIdx.x;
    if (e >= E) return;
    int p = atomicAdd(&cursor[dst[e]], 1);
    esrc[p] = src[e];
    ew[p]   = w[e];
}

// ---------------------------------------------------------------------------
// One wave per dst row; writes A2 = [feat|agg] in bf16 for GEMM2.
__global__ __launch_bounds__(256) void gather_A2(
    const float* __restrict__ y1, const unsigned short* __restrict__ feat_bf,
    const float* __restrict__ a1v, const float* __restrict__ b1v,
    const int* __restrict__ offs, const int* __restrict__ esrc,
    const float* __restrict__ ew,
    unsigned short* __restrict__ A2, int N)
{
    const int r    = (int)((blockIdx.x * 256u + threadIdx.x) >> 6);
    const int lane = threadIdx.x & 63;
    if (r >= N) return;
    const float2 a = *(const float2*)&a1v[2 * lane];
    const float2 b = *(const float2*)&b1v[2 * lane];
    int p = offs[r];
    const int end = offs[r + 1];
    float nx = 0.f, ny = 0.f, den = 0.f;
    for (; p + 1 < end; p += 2) {
        int   s0 = esrc[p],  s1 = esrc[p + 1];
        float w0 = ew[p],    w1 = ew[p + 1];
        float2 ya = *(const float2*)&y1[(size_t)s0 * 128 + 2 * lane];
        float2 yb = *(const float2*)&y1[(size_t)s1 * 128 + 2 * lane];
        nx = fmaf(w0, fmaf(a.x, ya.x, b.x), nx);
        ny = fmaf(w0, fmaf(a.y, ya.y, b.y), ny);
        nx = fmaf(w1, fmaf(a.x, yb.x, b.x), nx);
        ny = fmaf(w1, fmaf(a.y, yb.y, b.y), ny);
        den += w0 + w1;
    }
    if (p < end) {
        int   s0 = esrc[p];
        float w0 = ew[p];
        float2 ya = *(const float2*)&y1[(size_t)s0 * 128 + 2 * lane];
        nx = fmaf(w0, fmaf(a.x, ya.x, b.x), nx);
        ny = fmaf(w0, fmaf(a.y, ya.y, b.y), ny);
        den += w0;
    }
    float2 outv;
    if (den != 0.f) {
        float inv = 1.f / den;
        outv.x = nx * inv; outv.y = ny * inv;
    } else {
        float2 y = *(const float2*)&y1[(size_t)r * 128 + 2 * lane];
        outv.x = fmaf(a.x, y.x, b.x);
        outv.y = fmaf(a.y, y.y, b.y);
    }
    const size_t rb = (size_t)r * 256;
    *(ushort2*)&A2[rb + 2 * lane] = *(const ushort2*)&feat_bf[(size_t)r * 128 + 2 * lane];
    ushort2 ao; ao.x = f2bf(outv.x); ao.y = f2bf(outv.y);
    *(ushort2*)&A2[rb + 128 + 2 * lane] = ao;
}

// ---------------------------------------------------------------------------
__global__ __launch_bounds__(256) void finalize(
    const float* __restrict__ Y2,
    const float* __restrict__ a2, const float* __restrict__ b2,
    float* __restrict__ out, int N)
{
    const int row  = (int)((blockIdx.x * 256u + threadIdx.x) >> 6);
    const int lane = threadIdx.x & 63;
    if (row >= N) return;
    const size_t base = (size_t)row * 128;
    float v0 = fmaf(a2[lane],      Y2[base + lane],      b2[lane]);
    float v1 = fmaf(a2[lane + 64], Y2[base + lane + 64], b2[lane + 64]);
    float ss = fmaf(v0, v0, v1 * v1);
#pragma unroll
    for (int o = 32; o; o >>= 1) ss += __shfl_xor(ss, o, 64);
    float nrm = sqrtf(ss);
    float inv = (nrm == 0.f) ? 1.f : 1.f / nrm;
    out[base + lane]      = v0 * inv;
    out[base + lane + 64] = v1 * inv;
}

// ---------------------------------------------------------------------------
extern "C" void kernel_launch(void* const* d_in, const int* in_sizes, int n_in,
                              void* d_out, int out_size, void* d_ws, size_t ws_size,
                              hipStream_t stream)
{
    const float* feat   = (const float*)d_in[0];
    const float* w      = (const float*)d_in[1];
    const float* Q_w    = (const float*)d_in[2];
    const float* Q_b    = (const float*)d_in[3];
    const float* W_w    = (const float*)d_in[4];
    const float* W_b    = (const float*)d_in[5];
    const float* gamma2 = (const float*)d_in[6];
    const float* beta2  = (const float*)d_in[7];
    const int*   src    = (const int*)d_in[8];
    const int*   dst    = (const int*)d_in[9];

    const int N = in_sizes[0] / 128;   // 50000
    const int E = in_sizes[1];         // 800000

    // workspace layout
    float*          y1    = (float*)d_ws;                         // N*128 f32 (y1 then y2)
    unsigned short* A2    = (unsigned short*)(y1 + (size_t)N * 128); // N*256 bf16
    unsigned short* featb = A2 + (size_t)N * 256;                 // N*128 bf16
    unsigned short* Qwb   = featb + (size_t)N * 128;              // 128*128
    unsigned short* Wwb   = Qwb + 128 * 128;                      // 128*256
    int*   esrc   = (int*)(Wwb + 128 * 256);                      // E
    float* ew     = (float*)(esrc + E);                           // E
    int*   offs   = (int*)(ew + E);                               // N+1
    int*   cursor = offs + (N + 1);                               // N
    int*   cnt    = cursor + N;                                   // N   <- zeroed
    int*   bsum   = cnt + N;                                      // 64  <- zeroed
    uintptr_t sp  = ((uintptr_t)(bsum + 64) + 7) & ~(uintptr_t)7;
    double* stats = (double*)sp;                                  // 512 <- zeroed
    double* sum1 = stats, *sumsq1 = stats + 128, *sum2 = stats + 256, *sumsq2 = stats + 384;
    float* coefs = (float*)(stats + 512);                         // 512
    float* a1 = coefs, *b1 = coefs + 128, *a2 = coefs + 256, *b2 = coefs + 384;

    size_t zero_bytes = (size_t)((char*)(stats + 512) - (char*)cnt);
    hipMemsetAsync(cnt, 0, zero_bytes, stream);

    const float invN = 1.f / (float)N;
    const int gemm_blocks = (N + 63) / 64;
    const int nchunks = (N + 1023) / 1024;

    f32_to_bf16<<<(N * 128 + 1023) / 1024, 256, 0, stream>>>(feat, featb, N * 128);
    f32_to_bf16<<<(128 * 128 + 1023) / 1024, 256, 0, stream>>>(Q_w, Qwb, 128 * 128);
    f32_to_bf16<<<(128 * 256 + 1023) / 1024, 256, 0, stream>>>(W_w, Wwb, 128 * 256);

    gemm_mfma<128><<<gemm_blocks, 256, 0, stream>>>(featb, Qwb, Q_b, y1, N);
    colstats<<<(N + 255) / 256, 256, 0, stream>>>(y1, N, sum1, sumsq1);
    bn_coef<<<1, 128, 0, stream>>>(sum1, sumsq1, gamma2, beta2, a1, b1, invN);

    k_count<<<(E + 255) / 256, 256, 0, stream>>>(dst, cnt, E);
    k_scan1<<<nchunks, 256, 0, stream>>>(cnt, offs, bsum, N);
    k_scan2<<<1, 64, 0, stream>>>(bsum, nchunks);
    k_scan3<<<(N + 255) / 256, 256, 0, stream>>>(offs, cursor, bsum, N, E);
    k_fill<<<(E + 255) / 256, 256, 0, stream>>>(src, dst, w, cursor, esrc, ew, E);

    gather_A2<<<(N * 64 + 255) / 256, 256, 0, stream>>>(
        y1, featb, a1, b1, offs, esrc, ew, A2, N);

    gemm_mfma<256><<<gemm_blocks, 256, 0, stream>>>(A2, Wwb, W_b, y1 /*=y2*/, N);
    colstats<<<(N + 255) / 256, 256, 0, stream>>>(y1, N, sum2, sumsq2);
    bn_coef<<<1, 128, 0, stream>>>(sum2, sumsq2, gamma2, beta2, a2, b2, invN);
    finalize<<<(N + 3) / 4, 256, 0, stream>>>(y1, a2, b2, (float*)d_out, N);
}

// Round 4
// 356.497 us; speedup vs baseline: 2.1104x; 1.0795x over previous
//
#include <hip/hip_runtime.h>
#include <stdint.h>

// PinConv pipeline: bf16-MFMA GEMMs + CSR-gather aggregation (bf16 h).
// Stages: cast(feat,Qw,Ww)->bf16 | GEMM1(MFMA)+relu -> colstats -> bn coefs
//         apply_bn->h_bf16 | CSR build (count->scan->fill, packed int2)
//         gather(h_bf)+concat -> A2 (bf16) | GEMM2(MFMA)+relu -> colstats
//         -> bn coefs -> rownorm.

#define BN_EPS 1e-5f

typedef __attribute__((ext_vector_type(8))) short bf16x8;
typedef __attribute__((ext_vector_type(4))) float f32x4;

static __device__ __forceinline__ unsigned short f2bf(float f) {
    uint32_t u = __builtin_bit_cast(uint32_t, f);
    u += 0x7fffu + ((u >> 16) & 1u);          // round-to-nearest-even
    return (unsigned short)(u >> 16);
}
static __device__ __forceinline__ float bf_lo(uint32_t u) {
    return __builtin_bit_cast(float, u << 16);
}
static __device__ __forceinline__ float bf_hi(uint32_t u) {
    return __builtin_bit_cast(float, u & 0xffff0000u);
}

// ---------------------------------------------------------------------------
__global__ __launch_bounds__(256) void f32_to_bf16(
    const float* __restrict__ in, unsigned short* __restrict__ out, int n)
{
    int i = (blockIdx.x * 256 + threadIdx.x) * 4;
    if (i + 3 < n) {
        float4 v = *(const float4*)(in + i);
        ushort4 o;
        o.x = f2bf(v.x); o.y = f2bf(v.y); o.z = f2bf(v.z); o.w = f2bf(v.w);
        *(ushort4*)(out + i) = o;
    } else {
        for (int j = i; j < n; ++j) out[j] = f2bf(in[j]);
    }
}

// ---------------------------------------------------------------------------
// h = bf16(a[c]*y + b[c]), y:[N][128] f32 -> h:[N][128] bf16
__global__ __launch_bounds__(256) void apply_bn_bf16(
    const float* __restrict__ y, const float* __restrict__ a,
    const float* __restrict__ b, unsigned short* __restrict__ h, int n)
{
    int i = (blockIdx.x * 256 + threadIdx.x) * 4;
    if (i >= n) return;
    int c = i & 127;
    float4 v  = *(const float4*)(y + i);
    float4 av = *(const float4*)(a + c);
    float4 bv = *(const float4*)(b + c);
    ushort4 o;
    o.x = f2bf(fmaf(av.x, v.x, bv.x));
    o.y = f2bf(fmaf(av.y, v.y, bv.y));
    o.z = f2bf(fmaf(av.z, v.z, bv.z));
    o.w = f2bf(fmaf(av.w, v.w, bv.w));
    *(ushort4*)(h + i) = o;
}

// ---------------------------------------------------------------------------
// Y = relu(A @ B^T + bias), A:[N][K] bf16, B:[128][K] bf16, Y:[N][128] f32.
// Block tile 64x128, 4 waves (2x2), wave tile 32x64, BK=64.
template<int K>
__global__ __launch_bounds__(256) void gemm_mfma(
    const unsigned short* __restrict__ A,
    const unsigned short* __restrict__ B,
    const float* __restrict__ bias,
    float* __restrict__ Y, int N)
{
    constexpr int SA = 72;   // LDS row stride (bf16): pad 64->72 breaks bank aliasing
    __shared__ unsigned short As[64 * SA];
    __shared__ unsigned short Bs[128 * SA];

    const int tid  = threadIdx.x;
    const int lane = tid & 63;
    const int wv   = tid >> 6;
    const int wr   = wv >> 1;
    const int wc   = wv & 1;
    const int m15  = lane & 15;
    const int quad = lane >> 4;
    const int r0   = blockIdx.x * 64;

    f32x4 acc[2][4];
#pragma unroll
    for (int rt = 0; rt < 2; ++rt)
#pragma unroll
        for (int ct = 0; ct < 4; ++ct)
            acc[rt][ct] = (f32x4){0.f, 0.f, 0.f, 0.f};

    for (int kc = 0; kc < K; kc += 64) {
#pragma unroll
        for (int i = 0; i < 2; ++i) {
            int idx = i * 256 + tid;
            int row = idx >> 3, seg = idx & 7;
            int gr  = r0 + row; if (gr >= N) gr = N - 1;
            uint4 v = *(const uint4*)(A + (size_t)gr * K + kc + seg * 8);
            *(uint4*)(As + row * SA + seg * 8) = v;
        }
#pragma unroll
        for (int i = 0; i < 4; ++i) {
            int idx = i * 256 + tid;
            int row = idx >> 3, seg = idx & 7;
            uint4 v = *(const uint4*)(B + (size_t)row * K + kc + seg * 8);
            *(uint4*)(Bs + row * SA + seg * 8) = v;
        }
        __syncthreads();

#pragma unroll
        for (int ks = 0; ks < 64; ks += 32) {
            bf16x8 af[2], bfr[4];
#pragma unroll
            for (int rt = 0; rt < 2; ++rt)
                af[rt] = *(const bf16x8*)(As + (wr * 32 + rt * 16 + m15) * SA + ks + quad * 8);
#pragma unroll
            for (int ct = 0; ct < 4; ++ct)
                bfr[ct] = *(const bf16x8*)(Bs + (wc * 64 + ct * 16 + m15) * SA + ks + quad * 8);
#pragma unroll
            for (int rt = 0; rt < 2; ++rt)
#pragma unroll
                for (int ct = 0; ct < 4; ++ct)
                    acc[rt][ct] = __builtin_amdgcn_mfma_f32_16x16x32_bf16(
                        af[rt], bfr[ct], acc[rt][ct], 0, 0, 0);
        }
        __syncthreads();
    }

#pragma unroll
    for (int ct = 0; ct < 4; ++ct) {
        int col = wc * 64 + ct * 16 + m15;
        float bz = bias[col];
#pragma unroll
        for (int rt = 0; rt < 2; ++rt) {
#pragma unroll
            for (int reg = 0; reg < 4; ++reg) {
                int row = r0 + wr * 32 + rt * 16 + quad * 4 + reg;
                if (row < N)
                    Y[(size_t)row * 128 + col] = fmaxf(acc[rt][ct][reg] + bz, 0.f);
            }
        }
    }
}

// ---------------------------------------------------------------------------
__global__ __launch_bounds__(256) void colstats(
    const float* __restrict__ Y, int N,
    double* __restrict__ sum, double* __restrict__ sumsq)
{
    __shared__ float sh[2][256];
    const int col  = threadIdx.x & 127;
    const int half = threadIdx.x >> 7;
    const int rbeg = blockIdx.x * 256 + half;
    const int rend = min(N, blockIdx.x * 256 + 256);
    float s = 0.f, q = 0.f;
    for (int r = rbeg; r < rend; r += 2) {
        float v = Y[(size_t)r * 128 + col];
        s += v; q = fmaf(v, v, q);
    }
    sh[0][threadIdx.x] = s;
    sh[1][threadIdx.x] = q;
    __syncthreads();
    if (half == 0) {
        s = sh[0][col] + sh[0][col + 128];
        q = sh[1][col] + sh[1][col + 128];
        atomicAdd(&sum[col], (double)s);
        atomicAdd(&sumsq[col], (double)q);
    }
}

// ---------------------------------------------------------------------------
__global__ void bn_coef(const double* __restrict__ sum, const double* __restrict__ sumsq,
                        const float* __restrict__ gamma, const float* __restrict__ beta,
                        float* __restrict__ a, float* __restrict__ b, float invN)
{
    int j = threadIdx.x;  // 128 threads
    float mean = (float)(sum[j] * (double)invN);
    float var  = (float)(sumsq[j] * (double)invN) - mean * mean;
    float s = rsqrtf(var + BN_EPS) * gamma[j];
    a[j] = s;
    b[j] = fmaf(-mean, s, beta[j]);
}

// ---------------------------------------------------------------------------
__global__ __launch_bounds__(256) void k_count(
    const int* __restrict__ dst, int* __restrict__ cnt, int E)
{
    int e = blockIdx.x * 256 + threadIdx.x;
    if (e < E) atomicAdd(&cnt[dst[e]], 1);
}

__global__ __launch_bounds__(256) void k_scan1(
    const int* __restrict__ cnt, int* __restrict__ offs, int* __restrict__ bsum, int N)
{
    __shared__ int sh[256];
    const int tid  = threadIdx.x;
    const int base = blockIdx.x * 1024 + tid * 4;
    int v[4], s = 0;
#pragma unroll
    for (int j = 0; j < 4; ++j) {
        v[j] = (base + j < N) ? cnt[base + j] : 0;
        s += v[j];
    }
    sh[tid] = s;
    __syncthreads();
    for (int o = 1; o < 256; o <<= 1) {
        int t = (tid >= o) ? sh[tid - o] : 0;
        __syncthreads();
        sh[tid] += t;
        __syncthreads();
    }
    int run = sh[tid] - s;
#pragma unroll
    for (int j = 0; j < 4; ++j) {
        if (base + j < N) offs[base + j] = run;
        run += v[j];
    }
    if (tid == 255) bsum[blockIdx.x] = sh[255];
}

__global__ void k_scan2(int* __restrict__ bsum, int nb)
{
    if (threadIdx.x == 0) {
        int run = 0;
        for (int i = 0; i < nb; ++i) { int t = bsum[i]; bsum[i] = run; run += t; }
    }
}

__global__ __launch_bounds__(256) void k_scan3(
    int* __restrict__ offs, int* __restrict__ cursor,
    const int* __restrict__ bsum, int N, int E)
{
    int i = blockIdx.x * 256 + threadIdx.x;
    if (i < N) {
        int o = offs[i] + bsum[i >> 10];
        offs[i] = o;
        cursor[i] = o;
    }
    if (i == 0) offs[N] = E;
}

__global__ __launch_bounds__(256) void k_fill(
    const int* __restrict__ src, const int* __restrict__ dst,
    const float* __restrict__ w, int* __restrict__ cursor,
    int2* __restrict__ epack, int E)
{
    int e = blockIdx.x * 256 + threadIdx.x;
    if (e >= E) return;
    int p = atomicAdd(&cursor[dst[e]], 1);
    epack[p] = make_int2(src[e], __float_as_int(w[e]));
}

// ---------------------------------------------------------------------------
// One wave per dst row; h is bf16 with bn pre-applied. Writes A2=[feat|agg] bf16.
__global__ __launch_bounds__(256) void gather_A2(
    const unsigned short* __restrict__ h,
    const unsigned short* __restrict__ feat_bf,
    const int* __restrict__ offs, const int2* __restrict__ epack,
    unsigned short* __restrict__ A2, int N)
{
    const int r    = (int)((blockIdx.x * 256u + threadIdx.x) >> 6);
    const int lane = threadIdx.x & 63;
    if (r >= N) return;
    int p = offs[r];
    const int end = offs[r + 1];
    float nx = 0.f, ny = 0.f, den = 0.f;
    for (; p + 3 < end; p += 4) {
        int2 e0 = epack[p],     e1 = epack[p + 1];
        int2 e2 = epack[p + 2], e3 = epack[p + 3];
        uint32_t u0 = *(const uint32_t*)(h + (size_t)e0.x * 128 + 2 * lane);
        uint32_t u1 = *(const uint32_t*)(h + (size_t)e1.x * 128 + 2 * lane);
        uint32_t u2 = *(const uint32_t*)(h + (size_t)e2.x * 128 + 2 * lane);
        uint32_t u3 = *(const uint32_t*)(h + (size_t)e3.x * 128 + 2 * lane);
        float w0 = __int_as_float(e0.y), w1 = __int_as_float(e1.y);
        float w2 = __int_as_float(e2.y), w3 = __int_as_float(e3.y);
        nx = fmaf(w0, bf_lo(u0), nx); ny = fmaf(w0, bf_hi(u0), ny);
        nx = fmaf(w1, bf_lo(u1), nx); ny = fmaf(w1, bf_hi(u1), ny);
        nx = fmaf(w2, bf_lo(u2), nx); ny = fmaf(w2, bf_hi(u2), ny);
        nx = fmaf(w3, bf_lo(u3), nx); ny = fmaf(w3, bf_hi(u3), ny);
        den += (w0 + w1) + (w2 + w3);
    }
    for (; p < end; ++p) {
        int2 e0 = epack[p];
        float w0 = __int_as_float(e0.y);
        uint32_t u0 = *(const uint32_t*)(h + (size_t)e0.x * 128 + 2 * lane);
        nx = fmaf(w0, bf_lo(u0), nx); ny = fmaf(w0, bf_hi(u0), ny);
        den += w0;
    }
    float2 outv;
    if (den != 0.f) {
        float inv = 1.f / den;
        outv.x = nx * inv; outv.y = ny * inv;
    } else {
        uint32_t u = *(const uint32_t*)(h + (size_t)r * 128 + 2 * lane);
        outv.x = bf_lo(u); outv.y = bf_hi(u);
    }
    const size_t rb = (size_t)r * 256;
    *(uint32_t*)&A2[rb + 2 * lane] = *(const uint32_t*)&feat_bf[(size_t)r * 128 + 2 * lane];
    ushort2 ao; ao.x = f2bf(outv.x); ao.y = f2bf(outv.y);
    *(ushort2*)&A2[rb + 128 + 2 * lane] = ao;
}

// ---------------------------------------------------------------------------
__global__ __launch_bounds__(256) void finalize(
    const float* __restrict__ Y2,
    const float* __restrict__ a2, const float* __restrict__ b2,
    float* __restrict__ out, int N)
{
    const int row  = (int)((blockIdx.x * 256u + threadIdx.x) >> 6);
    const int lane = threadIdx.x & 63;
    if (row >= N) return;
    const size_t base = (size_t)row * 128;
    float v0 = fmaf(a2[lane],      Y2[base + lane],      b2[lane]);
    float v1 = fmaf(a2[lane + 64], Y2[base + lane + 64], b2[lane + 64]);
    float ss = fmaf(v0, v0, v1 * v1);
#pragma unroll
    for (int o = 32; o; o >>= 1) ss += __shfl_xor(ss, o, 64);
    float nrm = sqrtf(ss);
    float inv = (nrm == 0.f) ? 1.f : 1.f / nrm;
    out[base + lane]      = v0 * inv;
    out[base + lane + 64] = v1 * inv;
}

// ---------------------------------------------------------------------------
extern "C" void kernel_launch(void* const* d_in, const int* in_sizes, int n_in,
                              void* d_out, int out_size, void* d_ws, size_t ws_size,
                              hipStream_t stream)
{
    const float* feat   = (const float*)d_in[0];
    const float* w      = (const float*)d_in[1];
    const float* Q_w    = (const float*)d_in[2];
    const float* Q_b    = (const float*)d_in[3];
    const float* W_w    = (const float*)d_in[4];
    const float* W_b    = (const float*)d_in[5];
    const float* gamma2 = (const float*)d_in[6];
    const float* beta2  = (const float*)d_in[7];
    const int*   src    = (const int*)d_in[8];
    const int*   dst    = (const int*)d_in[9];

    const int N = in_sizes[0] / 128;   // 50000
    const int E = in_sizes[1];         // 800000

    // workspace layout
    float*          y1    = (float*)d_ws;                            // N*128 f32 (y1 then y2)
    unsigned short* A2    = (unsigned short*)(y1 + (size_t)N * 128); // N*256 bf16
    unsigned short* featb = A2 + (size_t)N * 256;                    // N*128 bf16
    unsigned short* Qwb   = featb + (size_t)N * 128;                 // 128*128
    unsigned short* Wwb   = Qwb + 128 * 128;                         // 128*256
    unsigned short* h_bf  = Wwb + 128 * 256;                         // N*128 bf16
    int2*  epack  = (int2*)(h_bf + (size_t)N * 128);                 // E (8B aligned)
    int*   offs   = (int*)(epack + E);                               // N+1
    int*   cursor = offs + (N + 1);                                  // N
    int*   cnt    = cursor + N;                                      // N   <- zeroed
    int*   bsum   = cnt + N;                                         // 64  <- zeroed
    uintptr_t sp  = ((uintptr_t)(bsum + 64) + 7) & ~(uintptr_t)7;
    double* stats = (double*)sp;                                     // 512 <- zeroed
    double* sum1 = stats, *sumsq1 = stats + 128, *sum2 = stats + 256, *sumsq2 = stats + 384;
    float* coefs = (float*)(stats + 512);                            // 512
    float* a1 = coefs, *b1 = coefs + 128, *a2 = coefs + 256, *b2 = coefs + 384;

    size_t zero_bytes = (size_t)((char*)(stats + 512) - (char*)cnt);
    hipMemsetAsync(cnt, 0, zero_bytes, stream);

    const float invN = 1.f / (float)N;
    const int gemm_blocks = (N + 63) / 64;
    const int nchunks = (N + 1023) / 1024;

    f32_to_bf16<<<(N * 128 + 1023) / 1024, 256, 0, stream>>>(feat, featb, N * 128);
    f32_to_bf16<<<(128 * 128 + 1023) / 1024, 256, 0, stream>>>(Q_w, Qwb, 128 * 128);
    f32_to_bf16<<<(128 * 256 + 1023) / 1024, 256, 0, stream>>>(W_w, Wwb, 128 * 256);

    gemm_mfma<128><<<gemm_blocks, 256, 0, stream>>>(featb, Qwb, Q_b, y1, N);
    colstats<<<(N + 255) / 256, 256, 0, stream>>>(y1, N, sum1, sumsq1);
    bn_coef<<<1, 128, 0, stream>>>(sum1, sumsq1, gamma2, beta2, a1, b1, invN);
    apply_bn_bf16<<<(N * 128 + 1023) / 1024, 256, 0, stream>>>(y1, a1, b1, h_bf, N * 128);

    k_count<<<(E + 255) / 256, 256, 0, stream>>>(dst, cnt, E);
    k_scan1<<<nchunks, 256, 0, stream>>>(cnt, offs, bsum, N);
    k_scan2<<<1, 64, 0, stream>>>(bsum, nchunks);
    k_scan3<<<(N + 255) / 256, 256, 0, stream>>>(offs, cursor, bsum, N, E);
    k_fill<<<(E + 255) / 256, 256, 0, stream>>>(src, dst, w, cursor, epack, E);

    gather_A2<<<(N * 64 + 255) / 256, 256, 0, stream>>>(
        h_bf, featb, offs, epack, A2, N);

    gemm_mfma<256><<<gemm_blocks, 256, 0, stream>>>(A2, Wwb, W_b, y1 /*=y2*/, N);
    colstats<<<(N + 255) / 256, 256, 0, stream>>>(y1, N, sum2, sumsq2);
    bn_coef<<<1, 128, 0, stream>>>(sum2, sumsq2, gamma2, beta2, a2, b2, invN);
    finalize<<<(N + 3) / 4, 256, 0, stream>>>(y1, a2, b2, (float*)d_out, N);
}

// Round 5
// 345.732 us; speedup vs baseline: 2.1761x; 1.0311x over previous
//
#include <hip/hip_runtime.h>
#include <stdint.h>

// PinConv pipeline: bf16-MFMA GEMMs (fused colstats) + CSR-gather aggregation.
// Round 5: locality-binned CSR build (k_bin coarse 512-dst buckets -> k_refine
// exact order), fused bn coefs into consumers, single-dispatch scan, A2 never
// materialized (GEMM2 stages [featb|aggb] from two pointers). 12 dispatches.

#define BN_EPS 1e-5f

typedef __attribute__((ext_vector_type(8))) short bf16x8;
typedef __attribute__((ext_vector_type(4))) float f32x4;

static __device__ __forceinline__ unsigned short f2bf(float f) {
    uint32_t u = __builtin_bit_cast(uint32_t, f);
    u += 0x7fffu + ((u >> 16) & 1u);          // round-to-nearest-even
    return (unsigned short)(u >> 16);
}
static __device__ __forceinline__ float bf_lo(uint32_t u) {
    return __builtin_bit_cast(float, u << 16);
}
static __device__ __forceinline__ float bf_hi(uint32_t u) {
    return __builtin_bit_cast(float, u & 0xffff0000u);
}

// ---------------------------------------------------------------------------
__global__ __launch_bounds__(256) void f32_to_bf16(
    const float* __restrict__ in, unsigned short* __restrict__ out, int n)
{
    int i = (blockIdx.x * 256 + threadIdx.x) * 4;
    if (i + 3 < n) {
        float4 v = *(const float4*)(in + i);
        ushort4 o;
        o.x = f2bf(v.x); o.y = f2bf(v.y); o.z = f2bf(v.z); o.w = f2bf(v.w);
        *(ushort4*)(out + i) = o;
    } else {
        for (int j = i; j < n; ++j) out[j] = f2bf(in[j]);
    }
}

// both weight matrices in one dispatch
__global__ __launch_bounds__(256) void cast_weights(
    const float* __restrict__ qw, const float* __restrict__ ww,
    unsigned short* __restrict__ qb, unsigned short* __restrict__ wb,
    int n1, int n2)
{
    int i = (blockIdx.x * 256 + threadIdx.x) * 4;
    if (i < n1) {
        float4 v = *(const float4*)(qw + i);
        ushort4 o;
        o.x = f2bf(v.x); o.y = f2bf(v.y); o.z = f2bf(v.z); o.w = f2bf(v.w);
        *(ushort4*)(qb + i) = o;
    } else {
        int j = i - n1;
        if (j < n2) {
            float4 v = *(const float4*)(ww + j);
            ushort4 o;
            o.x = f2bf(v.x); o.y = f2bf(v.y); o.z = f2bf(v.z); o.w = f2bf(v.w);
            *(ushort4*)(wb + j) = o;
        }
    }
}

// ---------------------------------------------------------------------------
// Y = relu(A @ B^T + bias); A rows come from A_lo (k<128) and A_hi (k>=128),
// each [N][128] bf16. B: [128][K] bf16. Fused column sum/sumsq (fp64 atomics).
template<int K>
__global__ __launch_bounds__(256) void gemm_bn(
    const unsigned short* __restrict__ A_lo,
    const unsigned short* __restrict__ A_hi,
    const unsigned short* __restrict__ B,
    const float* __restrict__ bias,
    float* __restrict__ Y,
    double* __restrict__ sum, double* __restrict__ sumsq, int N)
{
    constexpr int SA = 72;   // LDS row stride (bf16): pad 64->72 breaks bank aliasing
    __shared__ unsigned short As[64 * SA];
    __shared__ unsigned short Bs[128 * SA];
    __shared__ float bsum[128], bsq[128];

    const int tid  = threadIdx.x;
    const int lane = tid & 63;
    const int wv   = tid >> 6;
    const int wr   = wv >> 1;
    const int wc   = wv & 1;
    const int m15  = lane & 15;
    const int quad = lane >> 4;
    const int r0   = blockIdx.x * 64;

    if (tid < 128) { bsum[tid] = 0.f; bsq[tid] = 0.f; }

    f32x4 acc[2][4];
#pragma unroll
    for (int rt = 0; rt < 2; ++rt)
#pragma unroll
        for (int ct = 0; ct < 4; ++ct)
            acc[rt][ct] = (f32x4){0.f, 0.f, 0.f, 0.f};

    for (int kc = 0; kc < K; kc += 64) {
        const unsigned short* Ap = (kc < 128) ? A_lo : A_hi;
        const int koff = kc & 127;
#pragma unroll
        for (int i = 0; i < 2; ++i) {
            int idx = i * 256 + tid;
            int row = idx >> 3, seg = idx & 7;
            int gr  = r0 + row; if (gr >= N) gr = N - 1;
            uint4 v = *(const uint4*)(Ap + (size_t)gr * 128 + koff + seg * 8);
            *(uint4*)(As + row * SA + seg * 8) = v;
        }
#pragma unroll
        for (int i = 0; i < 4; ++i) {
            int idx = i * 256 + tid;
            int row = idx >> 3, seg = idx & 7;
            uint4 v = *(const uint4*)(B + (size_t)row * K + kc + seg * 8);
            *(uint4*)(Bs + row * SA + seg * 8) = v;
        }
        __syncthreads();

#pragma unroll
        for (int ks = 0; ks < 64; ks += 32) {
            bf16x8 af[2], bfr[4];
#pragma unroll
            for (int rt = 0; rt < 2; ++rt)
                af[rt] = *(const bf16x8*)(As + (wr * 32 + rt * 16 + m15) * SA + ks + quad * 8);
#pragma unroll
            for (int ct = 0; ct < 4; ++ct)
                bfr[ct] = *(const bf16x8*)(Bs + (wc * 64 + ct * 16 + m15) * SA + ks + quad * 8);
#pragma unroll
            for (int rt = 0; rt < 2; ++rt)
#pragma unroll
                for (int ct = 0; ct < 4; ++ct)
                    acc[rt][ct] = __builtin_amdgcn_mfma_f32_16x16x32_bf16(
                        af[rt], bfr[ct], acc[rt][ct], 0, 0, 0);
        }
        __syncthreads();
    }

    // epilogue: +bias, relu, store, and per-column sum/sumsq
#pragma unroll
    for (int ct = 0; ct < 4; ++ct) {
        int col = wc * 64 + ct * 16 + m15;
        float bz = bias[col];
        float s = 0.f, q = 0.f;
#pragma unroll
        for (int rt = 0; rt < 2; ++rt) {
#pragma unroll
            for (int reg = 0; reg < 4; ++reg) {
                int row = r0 + wr * 32 + rt * 16 + quad * 4 + reg;
                float v = fmaxf(acc[rt][ct][reg] + bz, 0.f);
                if (row < N) {
                    Y[(size_t)row * 128 + col] = v;
                } else {
                    v = 0.f;
                }
                s += v; q = fmaf(v, v, q);
            }
        }
        s += __shfl_xor(s, 16, 64); s += __shfl_xor(s, 32, 64);
        q += __shfl_xor(q, 16, 64); q += __shfl_xor(q, 32, 64);
        if (quad == 0) {
            atomicAdd(&bsum[col], s);
            atomicAdd(&bsq[col], q);
        }
    }
    __syncthreads();
    if (tid < 128) {
        atomicAdd(&sum[tid],   (double)bsum[tid]);
        atomicAdd(&sumsq[tid], (double)bsq[tid]);
    }
}

// ---------------------------------------------------------------------------
// h = bf16(a[c]*y + b[c]); coefs computed in-block from fp64 stats.
__global__ __launch_bounds__(256) void apply_bn_bf16(
    const float* __restrict__ y,
    const double* __restrict__ sum, const double* __restrict__ sumsq,
    const float* __restrict__ gamma, const float* __restrict__ beta,
    unsigned short* __restrict__ h, int n, double invN)
{
    __shared__ float sa[128], sb[128];
    const int t = threadIdx.x;
    if (t < 128) {
        float mean = (float)(sum[t] * invN);
        float var  = (float)(sumsq[t] * invN) - mean * mean;
        float s = rsqrtf(var + BN_EPS) * gamma[t];
        sa[t] = s;
        sb[t] = fmaf(-mean, s, beta[t]);
    }
    __syncthreads();
    int i = (blockIdx.x * 256 + t) * 4;
    if (i >= n) return;
    int c = i & 127;
    float4 v = *(const float4*)(y + i);
    ushort4 o;
    o.x = f2bf(fmaf(sa[c],     v.x, sb[c]));
    o.y = f2bf(fmaf(sa[c + 1], v.y, sb[c + 1]));
    o.z = f2bf(fmaf(sa[c + 2], v.z, sb[c + 2]));
    o.w = f2bf(fmaf(sa[c + 3], v.w, sb[c + 3]));
    *(ushort4*)(h + i) = o;
}

// ---------------------------------------------------------------------------
__global__ __launch_bounds__(256) void k_count(
    const int* __restrict__ dst, int* __restrict__ cnt, int E)
{
    int e = blockIdx.x * 256 + threadIdx.x;
    if (e < E) atomicAdd(&cnt[dst[e]], 1);
}

// single-dispatch exclusive scan of cnt[0..N) -> offs; bucket bases -> gcur.
__global__ __launch_bounds__(1024) void k_scan(
    const int* __restrict__ cnt, int* __restrict__ offs,
    int* __restrict__ gcur, int N, int E)
{
    __shared__ int wsum[16];
    __shared__ int tile_tot;
    const int tid = threadIdx.x, lane = tid & 63, wv = tid >> 6;
    int run = 0;
    for (int base = 0; base < N; base += 1024) {
        int i = base + tid;
        int v = (i < N) ? cnt[i] : 0;
        int s = v;
#pragma unroll
        for (int o = 1; o < 64; o <<= 1) {
            int t = __shfl_up(s, o, 64);
            if (lane >= o) s += t;
        }
        if (lane == 63) wsum[wv] = s;
        __syncthreads();
        if (wv == 0 && lane < 16) {
            int t = wsum[lane];
            int ss = t;
#pragma unroll
            for (int o = 1; o < 16; o <<= 1) {
                int u = __shfl_up(ss, o, 64);
                if (lane >= o) ss += u;
            }
            wsum[lane] = ss - t;               // exclusive wave offset
            if (lane == 15) tile_tot = ss;
        }
        __syncthreads();
        int excl = run + wsum[wv] + s - v;
        if (i < N) {
            offs[i] = excl;
            if ((i & 511) == 0) gcur[i >> 9] = excl;
        }
        run += tile_tot;
        __syncthreads();                       // wsum/tile_tot reuse
    }
    if (tid == 0) offs[N] = E;
}

// ---------------------------------------------------------------------------
// pass 1: bin edges into coarse buckets of 512 dsts (int4 records).
__global__ __launch_bounds__(256) void k_bin(
    const int* __restrict__ src, const int* __restrict__ dst,
    const float* __restrict__ w, int* __restrict__ gcur,
    int4* __restrict__ tmp, int E)
{
    __shared__ int hcnt[128];
    __shared__ int hbase[128];
    const int tid = threadIdx.x;
    if (tid < 128) hcnt[tid] = 0;
    __syncthreads();

    int d8[8], s8[8], slot8[8];
    float w8[8];
#pragma unroll
    for (int j = 0; j < 8; ++j) {
        int e = blockIdx.x * 2048 + j * 256 + tid;
        if (e < E) {
            d8[j] = dst[e]; s8[j] = src[e]; w8[j] = w[e];
            slot8[j] = atomicAdd(&hcnt[d8[j] >> 9], 1);
        } else d8[j] = -1;
    }
    __syncthreads();
    if (tid < 128 && hcnt[tid] > 0)
        hbase[tid] = atomicAdd(&gcur[tid], hcnt[tid]);
    __syncthreads();
#pragma unroll
    for (int j = 0; j < 8; ++j) {
        if (d8[j] >= 0) {
            int pos = hbase[d8[j] >> 9] + slot8[j];
            tmp[pos] = make_int4(s8[j], __float_as_int(w8[j]), d8[j], 0);
        }
    }
}

// pass 2: exact dst order within each bucket (L2-local scatter).
__global__ __launch_bounds__(256) void k_refine(
    const int4* __restrict__ tmp, const int* __restrict__ offs,
    int2* __restrict__ epack, int N)
{
    __shared__ int lcur[512];
    const int b   = blockIdx.x;
    const int d0  = b << 9;
    const int dlim = min(512, N - d0);
    for (int i = threadIdx.x; i < dlim; i += 256) lcur[i] = offs[d0 + i];
    __syncthreads();
    const int start = offs[d0];
    const int end   = offs[d0 + dlim];
    for (int p = start + threadIdx.x; p < end; p += 256) {
        int4 rec = tmp[p];
        int pos = atomicAdd(&lcur[rec.z - d0], 1);
        epack[pos] = make_int2(rec.x, rec.y);
    }
}

// ---------------------------------------------------------------------------
// One wave per dst row; h bf16 (bn applied). Writes agg only (bf16).
__global__ __launch_bounds__(256) void gather_agg(
    const unsigned short* __restrict__ h,
    const int* __restrict__ offs, const int2* __restrict__ epack,
    unsigned short* __restrict__ aggb, int N)
{
    const int r    = (int)((blockIdx.x * 256u + threadIdx.x) >> 6);
    const int lane = threadIdx.x & 63;
    if (r >= N) return;
    int p = offs[r];
    const int end = offs[r + 1];
    float nx = 0.f, ny = 0.f, den = 0.f;
    for (; p + 3 < end; p += 4) {
        int2 e0 = epack[p],     e1 = epack[p + 1];
        int2 e2 = epack[p + 2], e3 = epack[p + 3];
        uint32_t u0 = *(const uint32_t*)(h + (size_t)e0.x * 128 + 2 * lane);
        uint32_t u1 = *(const uint32_t*)(h + (size_t)e1.x * 128 + 2 * lane);
        uint32_t u2 = *(const uint32_t*)(h + (size_t)e2.x * 128 + 2 * lane);
        uint32_t u3 = *(const uint32_t*)(h + (size_t)e3.x * 128 + 2 * lane);
        float w0 = __int_as_float(e0.y), w1 = __int_as_float(e1.y);
        float w2 = __int_as_float(e2.y), w3 = __int_as_float(e3.y);
        nx = fmaf(w0, bf_lo(u0), nx); ny = fmaf(w0, bf_hi(u0), ny);
        nx = fmaf(w1, bf_lo(u1), nx); ny = fmaf(w1, bf_hi(u1), ny);
        nx = fmaf(w2, bf_lo(u2), nx); ny = fmaf(w2, bf_hi(u2), ny);
        nx = fmaf(w3, bf_lo(u3), nx); ny = fmaf(w3, bf_hi(u3), ny);
        den += (w0 + w1) + (w2 + w3);
    }
    for (; p < end; ++p) {
        int2 e0 = epack[p];
        float w0 = __int_as_float(e0.y);
        uint32_t u0 = *(const uint32_t*)(h + (size_t)e0.x * 128 + 2 * lane);
        nx = fmaf(w0, bf_lo(u0), nx); ny = fmaf(w0, bf_hi(u0), ny);
        den += w0;
    }
    float2 outv;
    if (den != 0.f) {
        float inv = 1.f / den;
        outv.x = nx * inv; outv.y = ny * inv;
    } else {
        uint32_t u = *(const uint32_t*)(h + (size_t)r * 128 + 2 * lane);
        outv.x = bf_lo(u); outv.y = bf_hi(u);
    }
    ushort2 ao; ao.x = f2bf(outv.x); ao.y = f2bf(outv.y);
    *(ushort2*)&aggb[(size_t)r * 128 + 2 * lane] = ao;
}

// ---------------------------------------------------------------------------
// bn2 affine (coefs from stats, in-block) + row L2 normalize.
__global__ __launch_bounds__(256) void finalize(
    const float* __restrict__ Y2,
    const double* __restrict__ sum, const double* __restrict__ sumsq,
    const float* __restrict__ gamma, const float* __restrict__ beta,
    float* __restrict__ out, int N, double invN)
{
    __shared__ float sa[128], sb[128];
    const int t = threadIdx.x;
    if (t < 128) {
        float mean = (float)(sum[t] * invN);
        float var  = (float)(sumsq[t] * invN) - mean * mean;
        float s = rsqrtf(var + BN_EPS) * gamma[t];
        sa[t] = s;
        sb[t] = fmaf(-mean, s, beta[t]);
    }
    __syncthreads();
    const int row  = (int)((blockIdx.x * 256u + t) >> 6);
    const int lane = t & 63;
    if (row >= N) return;
    const size_t base = (size_t)row * 128;
    float v0 = fmaf(sa[lane],      Y2[base + lane],      sb[lane]);
    float v1 = fmaf(sa[lane + 64], Y2[base + lane + 64], sb[lane + 64]);
    float ss = fmaf(v0, v0, v1 * v1);
#pragma unroll
    for (int o = 32; o; o >>= 1) ss += __shfl_xor(ss, o, 64);
    float nrm = sqrtf(ss);
    float inv = (nrm == 0.f) ? 1.f : 1.f / nrm;
    out[base + lane]      = v0 * inv;
    out[base + lane + 64] = v1 * inv;
}

// ---------------------------------------------------------------------------
extern "C" void kernel_launch(void* const* d_in, const int* in_sizes, int n_in,
                              void* d_out, int out_size, void* d_ws, size_t ws_size,
                              hipStream_t stream)
{
    const float* feat   = (const float*)d_in[0];
    const float* w      = (const float*)d_in[1];
    const float* Q_w    = (const float*)d_in[2];
    const float* Q_b    = (const float*)d_in[3];
    const float* W_w    = (const float*)d_in[4];
    const float* W_b    = (const float*)d_in[5];
    const float* gamma2 = (const float*)d_in[6];
    const float* beta2  = (const float*)d_in[7];
    const int*   src    = (const int*)d_in[8];
    const int*   dst    = (const int*)d_in[9];

    const int N = in_sizes[0] / 128;   // 50000
    const int E = in_sizes[1];         // 800000

    // workspace layout
    float*          y1    = (float*)d_ws;                            // N*128 f32 (y1 then y2)
    unsigned short* featb = (unsigned short*)(y1 + (size_t)N * 128); // N*128 bf16
    unsigned short* aggb  = featb + (size_t)N * 128;                 // N*128 bf16
    unsigned short* h_bf  = aggb + (size_t)N * 128;                  // N*128 bf16
    unsigned short* Qwb   = h_bf + (size_t)N * 128;                  // 128*128
    unsigned short* Wwb   = Qwb + 128 * 128;                         // 128*256
    int4*  tmp    = (int4*)(Wwb + 128 * 256);                        // E (16B aligned)
    int2*  epack  = (int2*)(tmp + E);                                // E
    int*   offs   = (int*)(epack + E);                               // N+2 (pad for align)
    int*   gcur   = offs + (N + 2);                                  // 128
    double* stats = (double*)(gcur + 128);                           // 512 <- zeroed
    double* sum1 = stats, *sumsq1 = stats + 128, *sum2 = stats + 256, *sumsq2 = stats + 384;
    int*   cnt    = (int*)(stats + 512);                             // N   <- zeroed

    // zero stats + cnt (contiguous)
    hipMemsetAsync(stats, 0, 512 * sizeof(double) + (size_t)N * sizeof(int), stream);

    const double invN = 1.0 / (double)N;
    const int gemm_blocks = (N + 63) / 64;
    const int NB = (N + 511) >> 9;   // coarse buckets (<=128)

    f32_to_bf16<<<(N * 128 + 1023) / 1024, 256, 0, stream>>>(feat, featb, N * 128);
    cast_weights<<<(128 * 128 + 128 * 256 + 1023) / 1024, 256, 0, stream>>>(
        Q_w, W_w, Qwb, Wwb, 128 * 128, 128 * 256);

    k_count<<<(E + 255) / 256, 256, 0, stream>>>(dst, cnt, E);
    k_scan<<<1, 1024, 0, stream>>>(cnt, offs, gcur, N, E);

    gemm_bn<128><<<gemm_blocks, 256, 0, stream>>>(
        featb, featb, Qwb, Q_b, y1, sum1, sumsq1, N);
    apply_bn_bf16<<<(N * 128 + 1023) / 1024, 256, 0, stream>>>(
        y1, sum1, sumsq1, gamma2, beta2, h_bf, N * 128, invN);

    k_bin<<<(E + 2047) / 2048, 256, 0, stream>>>(src, dst, w, gcur, tmp, E);
    k_refine<<<NB, 256, 0, stream>>>(tmp, offs, epack, N);

    gather_agg<<<(N * 64 + 255) / 256, 256, 0, stream>>>(h_bf, offs, epack, aggb, N);

    gemm_bn<256><<<gemm_blocks, 256, 0, stream>>>(
        featb, aggb, Wwb, W_b, y1 /*=y2*/, sum2, sumsq2, N);
    finalize<<<(N * 64 + 255) / 256, 256, 0, stream>>>(
        y1, sum2, sumsq2, gamma2, beta2, (float*)d_out, N, invN);
}

// Round 6
// 300.742 us; speedup vs baseline: 2.5016x; 1.1496x over previous
//
#include <hip/hip_runtime.h>
#include <stdint.h>

// PinConv pipeline: bf16-MFMA GEMMs (fused colstats, in-staging weight cast) +
// locality-binned CSR gather. Round 6: parallel 2-phase scan (was 46us
// single-WG), fused feat-cast+edge-count, weight cast folded into GEMM
// staging. 11 dispatches + 1 memset.

#define BN_EPS 1e-5f

typedef __attribute__((ext_vector_type(8))) short bf16x8;
typedef __attribute__((ext_vector_type(4))) float f32x4;

static __device__ __forceinline__ unsigned short f2bf(float f) {
    uint32_t u = __builtin_bit_cast(uint32_t, f);
    u += 0x7fffu + ((u >> 16) & 1u);          // round-to-nearest-even
    return (unsigned short)(u >> 16);
}
static __device__ __forceinline__ float bf_lo(uint32_t u) {
    return __builtin_bit_cast(float, u << 16);
}
static __device__ __forceinline__ float bf_hi(uint32_t u) {
    return __builtin_bit_cast(float, u & 0xffff0000u);
}

// ---------------------------------------------------------------------------
// Fused: blocks [0,CB) cast feat f32->bf16 (4 elems/thread); blocks [CB,..)
// histogram dst into cnt.
__global__ __launch_bounds__(256) void k_pre(
    const float* __restrict__ feat, unsigned short* __restrict__ featb, int nf,
    const int* __restrict__ dst, int* __restrict__ cnt, int E, int CB)
{
    if ((int)blockIdx.x < CB) {
        int i = (blockIdx.x * 256 + threadIdx.x) * 4;
        if (i + 3 < nf) {
            float4 v = *(const float4*)(feat + i);
            ushort4 o;
            o.x = f2bf(v.x); o.y = f2bf(v.y); o.z = f2bf(v.z); o.w = f2bf(v.w);
            *(ushort4*)(featb + i) = o;
        } else {
            for (int j = i; j < nf; ++j) featb[j] = f2bf(feat[j]);
        }
    } else {
        int e = (blockIdx.x - CB) * 256 + threadIdx.x;
        if (e < E) atomicAdd(&cnt[dst[e]], 1);
    }
}

// ---------------------------------------------------------------------------
// Scan phase 1: each block scans 4096 elems (1024 thr x int4). cnt is padded
// with zeros to 4096*gridDim, so unguarded vector loads are safe.
__global__ __launch_bounds__(1024) void k_scan_part(
    const int* __restrict__ cnt, int* __restrict__ offs,
    int* __restrict__ bsum)
{
    __shared__ int wsum[16];
    const int tid = threadIdx.x, lane = tid & 63, wv = tid >> 6;
    const int i = blockIdx.x * 4096 + tid * 4;
    int4 v = *(const int4*)(cnt + i);
    int s = v.x + v.y + v.z + v.w;
    int incl = s;
#pragma unroll
    for (int o = 1; o < 64; o <<= 1) {
        int t = __shfl_up(incl, o, 64);
        if (lane >= o) incl += t;
    }
    if (lane == 63) wsum[wv] = incl;
    __syncthreads();
    if (wv == 0 && lane < 16) {
        int t = wsum[lane];
        int ss = t;
#pragma unroll
        for (int o = 1; o < 16; o <<= 1) {
            int u = __shfl_up(ss, o, 64);
            if (lane >= o) ss += u;
        }
        wsum[lane] = ss - t;                   // exclusive wave offset
        if (lane == 15 && bsum) bsum[blockIdx.x] = ss;
    }
    __syncthreads();
    int e0 = wsum[wv] + incl - s;              // exclusive prefix of elem 0
    int4 o;
    o.x = e0; o.y = e0 + v.x; o.z = o.y + v.y; o.w = o.z + v.z;
    *(int4*)(offs + i) = o;
}

// Scan phase 2: add block prefix, emit gcur (512-bucket cursors), offs[N]=E.
__global__ __launch_bounds__(1024) void k_scan_fix(
    int* __restrict__ offs, const int* __restrict__ bsum,
    int* __restrict__ gcur, int N, int E)
{
    __shared__ int pre_s;
    const int tid = threadIdx.x;
    if (tid == 0) {
        int p = 0;
        for (int j = 0; j < (int)blockIdx.x; ++j) p += bsum[j];
        pre_s = p;
    }
    __syncthreads();
    const int pre = pre_s;
    const int i = blockIdx.x * 4096 + tid * 4;
    int4 v = *(const int4*)(offs + i);
    v.x += pre; v.y += pre; v.z += pre; v.w += pre;
    if (i + 3 < N) {
        *(int4*)(offs + i) = v;
    } else {
        int vv[4] = {v.x, v.y, v.z, v.w};
        for (int j = 0; j < 4; ++j) {
            int idx = i + j;
            if (idx < N) offs[idx] = vv[j];
            else if (idx == N) offs[idx] = E;
        }
    }
    if ((tid & 127) == 0 && i < N) gcur[i >> 9] = v.x;
}

// ---------------------------------------------------------------------------
// Y = relu(A @ B^T + bias); A rows from A_lo (k<128) / A_hi (k>=128), bf16.
// B: [128][K] f32, converted to bf16 during LDS staging. Fused col sum/sumsq.
template<int K>
__global__ __launch_bounds__(256) void gemm_bn(
    const unsigned short* __restrict__ A_lo,
    const unsigned short* __restrict__ A_hi,
    const float* __restrict__ B,
    const float* __restrict__ bias,
    float* __restrict__ Y,
    double* __restrict__ sum, double* __restrict__ sumsq, int N)
{
    constexpr int SA = 72;   // LDS row stride (bf16): pad 64->72 breaks bank aliasing
    __shared__ unsigned short As[64 * SA];
    __shared__ unsigned short Bs[128 * SA];
    __shared__ float bsum_s[128], bsq_s[128];

    const int tid  = threadIdx.x;
    const int lane = tid & 63;
    const int wv   = tid >> 6;
    const int wr   = wv >> 1;
    const int wc   = wv & 1;
    const int m15  = lane & 15;
    const int quad = lane >> 4;
    const int r0   = blockIdx.x * 64;

    if (tid < 128) { bsum_s[tid] = 0.f; bsq_s[tid] = 0.f; }

    f32x4 acc[2][4];
#pragma unroll
    for (int rt = 0; rt < 2; ++rt)
#pragma unroll
        for (int ct = 0; ct < 4; ++ct)
            acc[rt][ct] = (f32x4){0.f, 0.f, 0.f, 0.f};

    for (int kc = 0; kc < K; kc += 64) {
        const unsigned short* Ap = (kc < 128) ? A_lo : A_hi;
        const int koff = kc & 127;
        // A tile: 64 rows x 64 k, bf16, 16B/lane
#pragma unroll
        for (int i = 0; i < 2; ++i) {
            int idx = i * 256 + tid;
            int row = idx >> 3, seg = idx & 7;
            int gr  = r0 + row; if (gr >= N) gr = N - 1;
            uint4 v = *(const uint4*)(Ap + (size_t)gr * 128 + koff + seg * 8);
            *(uint4*)(As + row * SA + seg * 8) = v;
        }
        // B tile: 128 rows x 64 k, f32 -> bf16 convert in staging
#pragma unroll
        for (int i = 0; i < 8; ++i) {
            int idx = i * 256 + tid;           // 0..2047
            int row = idx >> 4, seg = idx & 15;
            float4 v = *(const float4*)(B + (size_t)row * K + kc + seg * 4);
            ushort4 o;
            o.x = f2bf(v.x); o.y = f2bf(v.y); o.z = f2bf(v.z); o.w = f2bf(v.w);
            *(ushort4*)(Bs + row * SA + seg * 4) = o;
        }
        __syncthreads();

#pragma unroll
        for (int ks = 0; ks < 64; ks += 32) {
            bf16x8 af[2], bfr[4];
#pragma unroll
            for (int rt = 0; rt < 2; ++rt)
                af[rt] = *(const bf16x8*)(As + (wr * 32 + rt * 16 + m15) * SA + ks + quad * 8);
#pragma unroll
            for (int ct = 0; ct < 4; ++ct)
                bfr[ct] = *(const bf16x8*)(Bs + (wc * 64 + ct * 16 + m15) * SA + ks + quad * 8);
#pragma unroll
            for (int rt = 0; rt < 2; ++rt)
#pragma unroll
                for (int ct = 0; ct < 4; ++ct)
                    acc[rt][ct] = __builtin_amdgcn_mfma_f32_16x16x32_bf16(
                        af[rt], bfr[ct], acc[rt][ct], 0, 0, 0);
        }
        __syncthreads();
    }

    // epilogue: +bias, relu, store, per-column sum/sumsq
#pragma unroll
    for (int ct = 0; ct < 4; ++ct) {
        int col = wc * 64 + ct * 16 + m15;
        float bz = bias[col];
        float s = 0.f, q = 0.f;
#pragma unroll
        for (int rt = 0; rt < 2; ++rt) {
#pragma unroll
            for (int reg = 0; reg < 4; ++reg) {
                int row = r0 + wr * 32 + rt * 16 + quad * 4 + reg;
                float v = fmaxf(acc[rt][ct][reg] + bz, 0.f);
                if (row < N) {
                    Y[(size_t)row * 128 + col] = v;
                } else {
                    v = 0.f;
                }
                s += v; q = fmaf(v, v, q);
            }
        }
        s += __shfl_xor(s, 16, 64); s += __shfl_xor(s, 32, 64);
        q += __shfl_xor(q, 16, 64); q += __shfl_xor(q, 32, 64);
        if (quad == 0) {
            atomicAdd(&bsum_s[col], s);
            atomicAdd(&bsq_s[col], q);
        }
    }
    __syncthreads();
    if (tid < 128) {
        atomicAdd(&sum[tid],   (double)bsum_s[tid]);
        atomicAdd(&sumsq[tid], (double)bsq_s[tid]);
    }
}

// ---------------------------------------------------------------------------
// h = bf16(a[c]*y + b[c]); coefs computed in-block from fp64 stats.
__global__ __launch_bounds__(256) void apply_bn_bf16(
    const float* __restrict__ y,
    const double* __restrict__ sum, const double* __restrict__ sumsq,
    const float* __restrict__ gamma, const float* __restrict__ beta,
    unsigned short* __restrict__ h, int n, double invN)
{
    __shared__ float sa[128], sb[128];
    const int t = threadIdx.x;
    if (t < 128) {
        float mean = (float)(sum[t] * invN);
        float var  = (float)(sumsq[t] * invN) - mean * mean;
        float s = rsqrtf(var + BN_EPS) * gamma[t];
        sa[t] = s;
        sb[t] = fmaf(-mean, s, beta[t]);
    }
    __syncthreads();
    int i = (blockIdx.x * 256 + t) * 4;
    if (i >= n) return;
    int c = i & 127;
    float4 v = *(const float4*)(y + i);
    ushort4 o;
    o.x = f2bf(fmaf(sa[c],     v.x, sb[c]));
    o.y = f2bf(fmaf(sa[c + 1], v.y, sb[c + 1]));
    o.z = f2bf(fmaf(sa[c + 2], v.z, sb[c + 2]));
    o.w = f2bf(fmaf(sa[c + 3], v.w, sb[c + 3]));
    *(ushort4*)(h + i) = o;
}

// ---------------------------------------------------------------------------
// pass 1: bin edges into coarse buckets of 512 dsts (int4 records).
__global__ __launch_bounds__(256) void k_bin(
    const int* __restrict__ src, const int* __restrict__ dst,
    const float* __restrict__ w, int* __restrict__ gcur,
    int4* __restrict__ tmp, int E)
{
    __shared__ int hcnt[128];
    __shared__ int hbase[128];
    const int tid = threadIdx.x;
    if (tid < 128) hcnt[tid] = 0;
    __syncthreads();

    int d8[8], s8[8], slot8[8];
    float w8[8];
#pragma unroll
    for (int j = 0; j < 8; ++j) {
        int e = blockIdx.x * 2048 + j * 256 + tid;
        if (e < E) {
            d8[j] = dst[e]; s8[j] = src[e]; w8[j] = w[e];
            slot8[j] = atomicAdd(&hcnt[d8[j] >> 9], 1);
        } else d8[j] = -1;
    }
    __syncthreads();
    if (tid < 128 && hcnt[tid] > 0)
        hbase[tid] = atomicAdd(&gcur[tid], hcnt[tid]);
    __syncthreads();
#pragma unroll
    for (int j = 0; j < 8; ++j) {
        if (d8[j] >= 0) {
            int pos = hbase[d8[j] >> 9] + slot8[j];
            tmp[pos] = make_int4(s8[j], __float_as_int(w8[j]), d8[j], 0);
        }
    }
}

// pass 2: exact dst order within each bucket (L2-local scatter).
__global__ __launch_bounds__(256) void k_refine(
    const int4* __restrict__ tmp, const int* __restrict__ offs,
    int2* __restrict__ epack, int N)
{
    __shared__ int lcur[512];
    const int b    = blockIdx.x;
    const int d0   = b << 9;
    const int dlim = min(512, N - d0);
    for (int i = threadIdx.x; i < dlim; i += 256) lcur[i] = offs[d0 + i];
    __syncthreads();
    const int start = offs[d0];
    const int end   = offs[d0 + dlim];
    for (int p = start + threadIdx.x; p < end; p += 256) {
        int4 rec = tmp[p];
        int pos = atomicAdd(&lcur[rec.z - d0], 1);
        epack[pos] = make_int2(rec.x, rec.y);
    }
}

// ---------------------------------------------------------------------------
// One wave per dst row; h bf16 (bn applied). Writes agg only (bf16).
__global__ __launch_bounds__(256) void gather_agg(
    const unsigned short* __restrict__ h,
    const int* __restrict__ offs, const int2* __restrict__ epack,
    unsigned short* __restrict__ aggb, int N)
{
    const int r    = (int)((blockIdx.x * 256u + threadIdx.x) >> 6);
    const int lane = threadIdx.x & 63;
    if (r >= N) return;
    int p = offs[r];
    const int end = offs[r + 1];
    float nx = 0.f, ny = 0.f, den = 0.f;
    for (; p + 3 < end; p += 4) {
        int2 e0 = epack[p],     e1 = epack[p + 1];
        int2 e2 = epack[p + 2], e3 = epack[p + 3];
        uint32_t u0 = *(const uint32_t*)(h + (size_t)e0.x * 128 + 2 * lane);
        uint32_t u1 = *(const uint32_t*)(h + (size_t)e1.x * 128 + 2 * lane);
        uint32_t u2 = *(const uint32_t*)(h + (size_t)e2.x * 128 + 2 * lane);
        uint32_t u3 = *(const uint32_t*)(h + (size_t)e3.x * 128 + 2 * lane);
        float w0 = __int_as_float(e0.y), w1 = __int_as_float(e1.y);
        float w2 = __int_as_float(e2.y), w3 = __int_as_float(e3.y);
        nx = fmaf(w0, bf_lo(u0), nx); ny = fmaf(w0, bf_hi(u0), ny);
        nx = fmaf(w1, bf_lo(u1), nx); ny = fmaf(w1, bf_hi(u1), ny);
        nx = fmaf(w2, bf_lo(u2), nx); ny = fmaf(w2, bf_hi(u2), ny);
        nx = fmaf(w3, bf_lo(u3), nx); ny = fmaf(w3, bf_hi(u3), ny);
        den += (w0 + w1) + (w2 + w3);
    }
    for (; p < end; ++p) {
        int2 e0 = epack[p];
        float w0 = __int_as_float(e0.y);
        uint32_t u0 = *(const uint32_t*)(h + (size_t)e0.x * 128 + 2 * lane);
        nx = fmaf(w0, bf_lo(u0), nx); ny = fmaf(w0, bf_hi(u0), ny);
        den += w0;
    }
    float2 outv;
    if (den != 0.f) {
        float inv = 1.f / den;
        outv.x = nx * inv; outv.y = ny * inv;
    } else {
        uint32_t u = *(const uint32_t*)(h + (size_t)r * 128 + 2 * lane);
        outv.x = bf_lo(u); outv.y = bf_hi(u);
    }
    ushort2 ao; ao.x = f2bf(outv.x); ao.y = f2bf(outv.y);
    *(ushort2*)&aggb[(size_t)r * 128 + 2 * lane] = ao;
}

// ---------------------------------------------------------------------------
// bn2 affine (coefs from stats, in-block) + row L2 normalize.
__global__ __launch_bounds__(256) void finalize(
    const float* __restrict__ Y2,
    const double* __restrict__ sum, const double* __restrict__ sumsq,
    const float* __restrict__ gamma, const float* __restrict__ beta,
    float* __restrict__ out, int N, double invN)
{
    __shared__ float sa[128], sb[128];
    const int t = threadIdx.x;
    if (t < 128) {
        float mean = (float)(sum[t] * invN);
        float var  = (float)(sumsq[t] * invN) - mean * mean;
        float s = rsqrtf(var + BN_EPS) * gamma[t];
        sa[t] = s;
        sb[t] = fmaf(-mean, s, beta[t]);
    }
    __syncthreads();
    const int row  = (int)((blockIdx.x * 256u + t) >> 6);
    const int lane = t & 63;
    if (row >= N) return;
    const size_t base = (size_t)row * 128;
    float v0 = fmaf(sa[lane],      Y2[base + lane],      sb[lane]);
    float v1 = fmaf(sa[lane + 64], Y2[base + lane + 64], sb[lane + 64]);
    float ss = fmaf(v0, v0, v1 * v1);
#pragma unroll
    for (int o = 32; o; o >>= 1) ss += __shfl_xor(ss, o, 64);
    float nrm = sqrtf(ss);
    float inv = (nrm == 0.f) ? 1.f : 1.f / nrm;
    out[base + lane]      = v0 * inv;
    out[base + lane + 64] = v1 * inv;
}

// ---------------------------------------------------------------------------
extern "C" void kernel_launch(void* const* d_in, const int* in_sizes, int n_in,
                              void* d_out, int out_size, void* d_ws, size_t ws_size,
                              hipStream_t stream)
{
    const float* feat   = (const float*)d_in[0];
    const float* w      = (const float*)d_in[1];
    const float* Q_w    = (const float*)d_in[2];
    const float* Q_b    = (const float*)d_in[3];
    const float* W_w    = (const float*)d_in[4];
    const float* W_b    = (const float*)d_in[5];
    const float* gamma2 = (const float*)d_in[6];
    const float* beta2  = (const float*)d_in[7];
    const int*   src    = (const int*)d_in[8];
    const int*   dst    = (const int*)d_in[9];

    const int N = in_sizes[0] / 128;   // 50000
    const int E = in_sizes[1];         // 800000

    const int SB = (N + 4095) / 4096;  // scan blocks (13)
    const int NP = SB * 4096;          // padded element count for scan

    // workspace layout
    float*          y1    = (float*)d_ws;                            // N*128 f32 (y1 then y2)
    unsigned short* featb = (unsigned short*)(y1 + (size_t)N * 128); // N*128 bf16
    unsigned short* aggb  = featb + (size_t)N * 128;                 // N*128 bf16
    unsigned short* h_bf  = aggb + (size_t)N * 128;                  // N*128 bf16
    int4*  tmp    = (int4*)(h_bf + (size_t)N * 128);                 // E (16B aligned)
    int2*  epack  = (int2*)(tmp + E);                                // E
    int*   offs   = (int*)(epack + E);                               // NP+4 (padded)
    int*   gcur   = offs + NP + 4;                                   // 128
    int*   bsum   = gcur + 128;                                      // SB (<=16)
    double* stats = (double*)(bsum + 16);                            // 512 <- zeroed
    double* sum1 = stats, *sumsq1 = stats + 128, *sum2 = stats + 256, *sumsq2 = stats + 384;
    int*   cnt    = (int*)(stats + 512);                             // NP  <- zeroed

    // zero stats + padded cnt (contiguous)
    hipMemsetAsync(stats, 0, 512 * sizeof(double) + (size_t)NP * sizeof(int), stream);

    const double invN = 1.0 / (double)N;
    const int gemm_blocks = (N + 63) / 64;
    const int NB = (N + 511) >> 9;     // coarse buckets (98)
    const int CB = (N * 128 / 4 + 255) / 256;   // cast blocks in k_pre

    k_pre<<<CB + (E + 255) / 256, 256, 0, stream>>>(
        feat, featb, N * 128, dst, cnt, E, CB);
    k_scan_part<<<SB, 1024, 0, stream>>>(cnt, offs, bsum);
    k_scan_fix<<<SB, 1024, 0, stream>>>(offs, bsum, gcur, N, E);

    k_bin<<<(E + 2047) / 2048, 256, 0, stream>>>(src, dst, w, gcur, tmp, E);
    k_refine<<<NB, 256, 0, stream>>>(tmp, offs, epack, N);

    gemm_bn<128><<<gemm_blocks, 256, 0, stream>>>(
        featb, featb, Q_w, Q_b, y1, sum1, sumsq1, N);
    apply_bn_bf16<<<(N * 128 + 1023) / 1024, 256, 0, stream>>>(
        y1, sum1, sumsq1, gamma2, beta2, h_bf, N * 128, invN);

    gather_agg<<<(N * 64 + 255) / 256, 256, 0, stream>>>(h_bf, offs, epack, aggb, N);

    gemm_bn<256><<<gemm_blocks, 256, 0, stream>>>(
        featb, aggb, W_w, W_b, y1 /*=y2*/, sum2, sumsq2, N);
    finalize<<<(N * 64 + 255) / 256, 256, 0, stream>>>(
        y1, sum2, sumsq2, gamma2, beta2, (float*)d_out, N, invN);
}